// Round 1
// baseline (1962.649 us; speedup 1.0000x reference)
//
#include <hip/hip_runtime.h>
#include <math.h>

#define BB 4
#define NN 1024
#define CC 768
#define HH 12
#define DH 64
#define C3 2304
#define KTOP 16
#define QROWS 4
#define KCH 32

// ---------------- Kernel 1: fused QKV projection (fp64 accumulate) ----------------
// qkv[m][c3] = sum_k x[m][k] * w[c3][k] + b[c3]; scatter to q/k (fp64), v (fp32)
__global__ __launch_bounds__(256) void qkv_proj(
    const float* __restrict__ x, const float* __restrict__ w,
    const float* __restrict__ bias,
    double* __restrict__ qws, double* __restrict__ kws, float* __restrict__ vws) {
    __shared__ float a_lds[64][17];
    __shared__ float b_lds[64][17];
    const int tid = threadIdx.x;
    const int m0 = blockIdx.x * 64, n0 = blockIdx.y * 64;
    const int ty = tid >> 4, tx = tid & 15;
    const int lr = tid >> 2, lc = (tid & 3) << 2;

    double acc[4][4];
#pragma unroll
    for (int i = 0; i < 4; ++i)
#pragma unroll
        for (int j = 0; j < 4; ++j) acc[i][j] = 0.0;

    for (int k0 = 0; k0 < CC; k0 += 16) {
        float4 av = *reinterpret_cast<const float4*>(&x[(size_t)(m0 + lr) * CC + k0 + lc]);
        float4 wv = *reinterpret_cast<const float4*>(&w[(size_t)(n0 + lr) * CC + k0 + lc]);
        __syncthreads();
        a_lds[lr][lc + 0] = av.x; a_lds[lr][lc + 1] = av.y;
        a_lds[lr][lc + 2] = av.z; a_lds[lr][lc + 3] = av.w;
        b_lds[lr][lc + 0] = wv.x; b_lds[lr][lc + 1] = wv.y;
        b_lds[lr][lc + 2] = wv.z; b_lds[lr][lc + 3] = wv.w;
        __syncthreads();
#pragma unroll
        for (int kk = 0; kk < 16; ++kk) {
            double a0 = (double)a_lds[ty + 0][kk];
            double a1 = (double)a_lds[ty + 16][kk];
            double a2 = (double)a_lds[ty + 32][kk];
            double a3 = (double)a_lds[ty + 48][kk];
            double w0 = (double)b_lds[tx + 0][kk];
            double w1 = (double)b_lds[tx + 16][kk];
            double w2 = (double)b_lds[tx + 32][kk];
            double w3 = (double)b_lds[tx + 48][kk];
            acc[0][0] = fma(a0, w0, acc[0][0]); acc[0][1] = fma(a0, w1, acc[0][1]);
            acc[0][2] = fma(a0, w2, acc[0][2]); acc[0][3] = fma(a0, w3, acc[0][3]);
            acc[1][0] = fma(a1, w0, acc[1][0]); acc[1][1] = fma(a1, w1, acc[1][1]);
            acc[1][2] = fma(a1, w2, acc[1][2]); acc[1][3] = fma(a1, w3, acc[1][3]);
            acc[2][0] = fma(a2, w0, acc[2][0]); acc[2][1] = fma(a2, w1, acc[2][1]);
            acc[2][2] = fma(a2, w2, acc[2][2]); acc[2][3] = fma(a2, w3, acc[2][3]);
            acc[3][0] = fma(a3, w0, acc[3][0]); acc[3][1] = fma(a3, w1, acc[3][1]);
            acc[3][2] = fma(a3, w2, acc[3][2]); acc[3][3] = fma(a3, w3, acc[3][3]);
        }
    }

#pragma unroll
    for (int i = 0; i < 4; ++i) {
#pragma unroll
        for (int j = 0; j < 4; ++j) {
            int m = m0 + ty + i * 16;
            int col = n0 + tx + j * 16;
            double val = acc[i][j] + (double)bias[col];
            int t = col / CC;
            int rem = col - t * CC;
            int h = rem >> 6, d = rem & 63;
            int b = m >> 10, n = m & 1023;
            size_t off = (((size_t)(b * HH + h)) * NN + n) * DH + d;
            if (t == 0) qws[off] = val;
            else if (t == 1) kws[off] = val;
            else vws[off] = (float)val;
        }
    }
}

// ---------------- Kernel 2: scores (fp64) + top-16 + sparse attn write + AV ----------------
__global__ __launch_bounds__(256) void attn_topk(
    const double* __restrict__ qws, const double* __restrict__ kws,
    const float* __restrict__ vws,
    float* __restrict__ attn_out, float* __restrict__ xattn) {
    __shared__ double k_lds[KCH][DH + 1];       // 16.6 KB
    __shared__ double s_lds[QROWS][NN];         // 32 KB
    __shared__ double q_lds[QROWS][DH];         // 2 KB
    __shared__ double sel_sval[QROWS][KTOP];
    __shared__ int    sel_idx[QROWS][KTOP];
    __shared__ float  sel_p[QROWS][KTOP];

    const int blk = blockIdx.x;
    const int bh = blk >> 8;                    // /(NN/QROWS)=256
    const int q0 = (blk & 255) * QROWS;
    const int tid = threadIdx.x;
    const int wave = tid >> 6, lane = tid & 63;
    const int jl = lane & 31;
    const int dh0 = (lane >> 5) * 32;

    // load Q rows
    {
        int r = tid >> 6, d = tid & 63;
        q_lds[r][d] = qws[((size_t)bh * NN + q0 + r) * DH + d];
    }
    const double* kbase = kws + (size_t)bh * NN * DH;

    for (int kc = 0; kc < NN; kc += KCH) {
        __syncthreads();  // previous chunk fully consumed (also covers q_lds on iter 0)
        for (int i = tid; i < KCH * DH; i += 256) {
            k_lds[i >> 6][i & 63] = kbase[(size_t)kc * DH + i];
        }
        __syncthreads();
        double s = 0.0;
#pragma unroll
        for (int d = 0; d < 32; ++d)
            s = fma(q_lds[wave][dh0 + d], k_lds[jl][dh0 + d], s);
        s += __shfl_xor(s, 32);
        if (lane < 32) s_lds[wave][kc + jl] = s * 0.125;
    }
    // per-wave from here: each wave owns row r = wave (its own s_lds row)

    const int r = wave;
    // top-16 selection (fp64 exact ranking, tie -> lower index)
    for (int t = 0; t < KTOP; ++t) {
        double best = -1e300;
        int bidx = NN;
#pragma unroll
        for (int i = 0; i < NN / 64; ++i) {
            int j = i * 64 + lane;
            double v = s_lds[r][j];
            if (v > best || (v == best && j < bidx)) { best = v; bidx = j; }
        }
#pragma unroll
        for (int off = 32; off; off >>= 1) {
            double ov = __shfl_xor(best, off);
            int oi = __shfl_xor(bidx, off);
            if (ov > best || (ov == best && oi < bidx)) { best = ov; bidx = oi; }
        }
        if (lane == 0) {
            sel_sval[r][t] = best;
            sel_idx[r][t] = bidx;
            s_lds[r][bidx] = -1e300;  // mask for next round
        }
    }
    // probs = softmax over the 16 selected scores (full-softmax denom cancels; clip inert)
    {
        double m = sel_sval[r][0];
        double e = (lane < KTOP) ? exp(sel_sval[r][lane] - m) : 0.0;
        double sum = e;
#pragma unroll
        for (int off = 32; off; off >>= 1) sum += __shfl_xor(sum, off);
        if (lane < KTOP) sel_p[r][lane] = (float)(e / sum);
    }

    // broadcast selection to registers
    int   si[KTOP];
    float sp[KTOP];
#pragma unroll
    for (int t = 0; t < KTOP; ++t) { si[t] = sel_idx[r][t]; sp[t] = sel_p[r][t]; }

    // write sparse attn row (zeros + 16 values)
    const int qn = q0 + r;
    float* arow = attn_out + ((size_t)bh * NN + qn) * NN;
#pragma unroll
    for (int i = 0; i < NN / 64; ++i) {
        int j = i * 64 + lane;
        float val = 0.0f;
#pragma unroll
        for (int t = 0; t < KTOP; ++t)
            if (si[t] == j) val = sp[t];
        arow[j] = val;
    }

    // AV: o[d] = sum_t p_t * v[sel_t][d]   (lane = d)
    {
        const float* vbase = vws + (size_t)bh * NN * DH;
        double o = 0.0;
#pragma unroll
        for (int t = 0; t < KTOP; ++t)
            o += (double)sp[t] * (double)vbase[(size_t)si[t] * DH + lane];
        int b = bh / HH, h = bh - b * HH;
        xattn[((size_t)b * NN + qn) * CC + h * DH + lane] = (float)o;
    }
}

// ---------------- Kernel 3: output projection ----------------
__global__ __launch_bounds__(256) void out_proj(
    const float* __restrict__ a, const float* __restrict__ w,
    const float* __restrict__ bias, float* __restrict__ out) {
    __shared__ float a_lds[64][17];
    __shared__ float b_lds[64][17];
    const int tid = threadIdx.x;
    const int m0 = blockIdx.x * 64, n0 = blockIdx.y * 64;
    const int ty = tid >> 4, tx = tid & 15;
    const int lr = tid >> 2, lc = (tid & 3) << 2;

    double acc[4][4];
#pragma unroll
    for (int i = 0; i < 4; ++i)
#pragma unroll
        for (int j = 0; j < 4; ++j) acc[i][j] = 0.0;

    for (int k0 = 0; k0 < CC; k0 += 16) {
        float4 av = *reinterpret_cast<const float4*>(&a[(size_t)(m0 + lr) * CC + k0 + lc]);
        float4 wv = *reinterpret_cast<const float4*>(&w[(size_t)(n0 + lr) * CC + k0 + lc]);
        __syncthreads();
        a_lds[lr][lc + 0] = av.x; a_lds[lr][lc + 1] = av.y;
        a_lds[lr][lc + 2] = av.z; a_lds[lr][lc + 3] = av.w;
        b_lds[lr][lc + 0] = wv.x; b_lds[lr][lc + 1] = wv.y;
        b_lds[lr][lc + 2] = wv.z; b_lds[lr][lc + 3] = wv.w;
        __syncthreads();
#pragma unroll
        for (int kk = 0; kk < 16; ++kk) {
            double a0 = (double)a_lds[ty + 0][kk];
            double a1 = (double)a_lds[ty + 16][kk];
            double a2 = (double)a_lds[ty + 32][kk];
            double a3 = (double)a_lds[ty + 48][kk];
            double w0 = (double)b_lds[tx + 0][kk];
            double w1 = (double)b_lds[tx + 16][kk];
            double w2 = (double)b_lds[tx + 32][kk];
            double w3 = (double)b_lds[tx + 48][kk];
            acc[0][0] = fma(a0, w0, acc[0][0]); acc[0][1] = fma(a0, w1, acc[0][1]);
            acc[0][2] = fma(a0, w2, acc[0][2]); acc[0][3] = fma(a0, w3, acc[0][3]);
            acc[1][0] = fma(a1, w0, acc[1][0]); acc[1][1] = fma(a1, w1, acc[1][1]);
            acc[1][2] = fma(a1, w2, acc[1][2]); acc[1][3] = fma(a1, w3, acc[1][3]);
            acc[2][0] = fma(a2, w0, acc[2][0]); acc[2][1] = fma(a2, w1, acc[2][1]);
            acc[2][2] = fma(a2, w2, acc[2][2]); acc[2][3] = fma(a2, w3, acc[2][3]);
            acc[3][0] = fma(a3, w0, acc[3][0]); acc[3][1] = fma(a3, w1, acc[3][1]);
            acc[3][2] = fma(a3, w2, acc[3][2]); acc[3][3] = fma(a3, w3, acc[3][3]);
        }
    }

#pragma unroll
    for (int i = 0; i < 4; ++i) {
#pragma unroll
        for (int j = 0; j < 4; ++j) {
            int m = m0 + ty + i * 16;
            int n = n0 + tx + j * 16;
            out[(size_t)m * CC + n] = (float)(acc[i][j] + (double)bias[n]);
        }
    }
}

extern "C" void kernel_launch(void* const* d_in, const int* in_sizes, int n_in,
                              void* d_out, int out_size, void* d_ws, size_t ws_size,
                              hipStream_t stream) {
    const float* x     = (const float*)d_in[0];
    const float* w_in  = (const float*)d_in[1];
    const float* b_in  = (const float*)d_in[2];
    const float* w_out = (const float*)d_in[3];
    const float* b_out = (const float*)d_in[4];

    float* xout     = (float*)d_out;                       // [B][N][C]  = 3,145,728
    float* attn_out = (float*)d_out + (size_t)BB * NN * CC; // [B][H][N][N]

    char* ws = (char*)d_ws;
    double* qws  = (double*)ws;                                   // 25,165,824 B
    double* kws  = (double*)(ws + 25165824);                      // 25,165,824 B
    float*  vws  = (float*)(ws + 50331648);                       // 12,582,912 B
    float*  xatt = (float*)(ws + 62914560);                       // 12,582,912 B

    hipLaunchKernelGGL(qkv_proj, dim3(64, 36), dim3(256), 0, stream,
                       x, w_in, b_in, qws, kws, vws);
    hipLaunchKernelGGL(attn_topk, dim3(BB * HH * (NN / QROWS)), dim3(256), 0, stream,
                       qws, kws, vws, attn_out, xatt);
    hipLaunchKernelGGL(out_proj, dim3(64, 12), dim3(256), 0, stream,
                       xatt, w_out, b_out, xout);
}

// Round 2
// 1094.309 us; speedup vs baseline: 1.7935x; 1.7935x over previous
//
#include <hip/hip_runtime.h>
#include <math.h>

#define BB 4
#define NN 1024
#define CC 768
#define HH 12
#define DH 64
#define KTOP 16

// ---------------- Kernel 1: fused QKV projection (fp64 accumulate) ----------------
// (unchanged from passing R1 version)
__global__ __launch_bounds__(256) void qkv_proj(
    const float* __restrict__ x, const float* __restrict__ w,
    const float* __restrict__ bias,
    double* __restrict__ qws, double* __restrict__ kws, float* __restrict__ vws) {
    __shared__ float a_lds[64][17];
    __shared__ float b_lds[64][17];
    const int tid = threadIdx.x;
    const int m0 = blockIdx.x * 64, n0 = blockIdx.y * 64;
    const int ty = tid >> 4, tx = tid & 15;
    const int lr = tid >> 2, lc = (tid & 3) << 2;

    double acc[4][4];
#pragma unroll
    for (int i = 0; i < 4; ++i)
#pragma unroll
        for (int j = 0; j < 4; ++j) acc[i][j] = 0.0;

    for (int k0 = 0; k0 < CC; k0 += 16) {
        float4 av = *reinterpret_cast<const float4*>(&x[(size_t)(m0 + lr) * CC + k0 + lc]);
        float4 wv = *reinterpret_cast<const float4*>(&w[(size_t)(n0 + lr) * CC + k0 + lc]);
        __syncthreads();
        a_lds[lr][lc + 0] = av.x; a_lds[lr][lc + 1] = av.y;
        a_lds[lr][lc + 2] = av.z; a_lds[lr][lc + 3] = av.w;
        b_lds[lr][lc + 0] = wv.x; b_lds[lr][lc + 1] = wv.y;
        b_lds[lr][lc + 2] = wv.z; b_lds[lr][lc + 3] = wv.w;
        __syncthreads();
#pragma unroll
        for (int kk = 0; kk < 16; ++kk) {
            double a0 = (double)a_lds[ty + 0][kk];
            double a1 = (double)a_lds[ty + 16][kk];
            double a2 = (double)a_lds[ty + 32][kk];
            double a3 = (double)a_lds[ty + 48][kk];
            double w0 = (double)b_lds[tx + 0][kk];
            double w1 = (double)b_lds[tx + 16][kk];
            double w2 = (double)b_lds[tx + 32][kk];
            double w3 = (double)b_lds[tx + 48][kk];
            acc[0][0] = fma(a0, w0, acc[0][0]); acc[0][1] = fma(a0, w1, acc[0][1]);
            acc[0][2] = fma(a0, w2, acc[0][2]); acc[0][3] = fma(a0, w3, acc[0][3]);
            acc[1][0] = fma(a1, w0, acc[1][0]); acc[1][1] = fma(a1, w1, acc[1][1]);
            acc[1][2] = fma(a1, w2, acc[1][2]); acc[1][3] = fma(a1, w3, acc[1][3]);
            acc[2][0] = fma(a2, w0, acc[2][0]); acc[2][1] = fma(a2, w1, acc[2][1]);
            acc[2][2] = fma(a2, w2, acc[2][2]); acc[2][3] = fma(a2, w3, acc[2][3]);
            acc[3][0] = fma(a3, w0, acc[3][0]); acc[3][1] = fma(a3, w1, acc[3][1]);
            acc[3][2] = fma(a3, w2, acc[3][2]); acc[3][3] = fma(a3, w3, acc[3][3]);
        }
    }

#pragma unroll
    for (int i = 0; i < 4; ++i) {
#pragma unroll
        for (int j = 0; j < 4; ++j) {
            int m = m0 + ty + i * 16;
            int col = n0 + tx + j * 16;
            double val = acc[i][j] + (double)bias[col];
            int t = col / CC;
            int rem = col - t * CC;
            int h = rem >> 6, d = rem & 63;
            int b = m >> 10, n = m & 1023;
            size_t off = (((size_t)(b * HH + h)) * NN + n) * DH + d;
            if (t == 0) qws[off] = val;
            else if (t == 1) kws[off] = val;
            else vws[off] = (float)val;
        }
    }
}

// ---------------- Kernel 2a: fp32 scores GEMM -> raw scores into attn region ----------------
// tile 128 rows x 128 cols per chunk, 8x8 per lane, XOR-swizzled LDS (slot = d4 ^ (row>>3)).
__global__ __launch_bounds__(256) void scores32(
    const double* __restrict__ q64, const double* __restrict__ k64,
    float* __restrict__ attn_out) {
    __shared__ float qs[128][64];
    __shared__ float ks[128][64];
    const int bh = blockIdx.y;
    const int m0 = blockIdx.x * 128;
    const int tid = threadIdx.x;
    const int ty = tid >> 4, tx = tid & 15;

    const double* qb = q64 + ((size_t)bh * NN + m0) * DH;
    const double* kb = k64 + (size_t)bh * NN * DH;

    // stage q tile once (convert fp64->fp32, fold 0.125 scale, swizzle slots)
#pragma unroll
    for (int wv = 0; wv < 8; ++wv) {
        int e = tid + 256 * wv;             // 2048 float4 elems: 128 rows x 16 d4
        int row = e >> 4, d4 = e & 15;
        const double* src = qb + (size_t)row * DH + d4 * 4;
        float4 f;
        f.x = (float)(src[0] * 0.125); f.y = (float)(src[1] * 0.125);
        f.z = (float)(src[2] * 0.125); f.w = (float)(src[3] * 0.125);
        ((float4*)qs[row])[d4 ^ ((row >> 3) & 15)] = f;
    }

    float* orow0 = attn_out + ((size_t)bh * NN + m0) * NN;

    for (int c0 = 0; c0 < NN; c0 += 128) {
        __syncthreads();   // previous chunk's ks fully consumed (covers qs on iter 0 too)
#pragma unroll
        for (int wv = 0; wv < 8; ++wv) {
            int e = tid + 256 * wv;
            int col = e >> 4, d4 = e & 15;
            const double* src = kb + (size_t)(c0 + col) * DH + d4 * 4;
            float4 f;
            f.x = (float)src[0]; f.y = (float)src[1];
            f.z = (float)src[2]; f.w = (float)src[3];
            ((float4*)ks[col])[d4 ^ ((col >> 3) & 15)] = f;
        }
        __syncthreads();

        float acc[8][8];
#pragma unroll
        for (int i = 0; i < 8; ++i)
#pragma unroll
            for (int j = 0; j < 8; ++j) acc[i][j] = 0.0f;

#pragma unroll
        for (int d4 = 0; d4 < 16; ++d4) {
            float4 a4[8];
#pragma unroll
            for (int i = 0; i < 8; ++i)
                a4[i] = ((float4*)qs[8 * ty + i])[d4 ^ ty];
#pragma unroll
            for (int j = 0; j < 8; ++j) {
                float4 b4 = ((float4*)ks[8 * tx + j])[d4 ^ tx];
#pragma unroll
                for (int i = 0; i < 8; ++i) {
                    acc[i][j] = fmaf(a4[i].x, b4.x, acc[i][j]);
                    acc[i][j] = fmaf(a4[i].y, b4.y, acc[i][j]);
                    acc[i][j] = fmaf(a4[i].z, b4.z, acc[i][j]);
                    acc[i][j] = fmaf(a4[i].w, b4.w, acc[i][j]);
                }
            }
        }

        // store raw scores (scale already folded into q)
#pragma unroll
        for (int i = 0; i < 8; ++i) {
#pragma unroll
            for (int jj = 0; jj < 2; ++jj) {
                float4 o;
                o.x = acc[i][4 * jj + 0]; o.y = acc[i][4 * jj + 1];
                o.z = acc[i][4 * jj + 2]; o.w = acc[i][4 * jj + 3];
                *(float4*)&orow0[(size_t)(8 * ty + i) * NN + c0 + 8 * tx + 4 * jj] = o;
            }
        }
    }
}

// ---------------- Kernel 2b: top-20 fp32 candidates -> fp64 exact top-16 + AV + writes ----
__global__ __launch_bounds__(256) void topk_select(
    const double* __restrict__ q64, const double* __restrict__ k64,
    const float* __restrict__ v32,
    float* __restrict__ attn_out, float* __restrict__ xatt) {
    const int blk = blockIdx.x;
    const int wave = threadIdx.x >> 6, lane = threadIdx.x & 63;
    const int bh = blk >> 8;
    const int qn = ((blk & 255) << 2) | wave;

    float* srow = attn_out + ((size_t)bh * NN + qn) * NN;

    // load 16 scores into regs: s[4i+k] <-> col i*256 + lane*4 + k
    float s[16];
#pragma unroll
    for (int i = 0; i < 4; ++i) {
        float4 t = *(const float4*)&srow[i * 256 + lane * 4];
        s[4 * i + 0] = t.x; s[4 * i + 1] = t.y; s[4 * i + 2] = t.z; s[4 * i + 3] = t.w;
    }

    // extract top-20 by fp32 (tie -> lower column index)
    int cand = 0;
#pragma unroll 1
    for (int t = 0; t < 20; ++t) {
        float bv = -3.4e38f; int bi = (1 << 30);
#pragma unroll
        for (int r = 0; r < 16; ++r) {
            int c = ((r >> 2) << 8) + (lane << 2) + (r & 3);
            bool g = (s[r] > bv);
            bv = g ? s[r] : bv;
            bi = g ? c : bi;
        }
#pragma unroll
        for (int off = 32; off; off >>= 1) {
            float ov = __shfl_xor(bv, off);
            int oi = __shfl_xor(bi, off);
            if (ov > bv || (ov == bv && oi < bi)) { bv = ov; bi = oi; }
        }
        if (lane == t) cand = bi;
#pragma unroll
        for (int r = 0; r < 16; ++r) {
            int c = ((r >> 2) << 8) + (lane << 2) + (r & 3);
            if (c == bi) s[r] = -3.4e38f;
        }
    }

    // fp64 rescore of the 20 candidates (lane <-> d, coalesced 512B k-row loads)
    const double* qrow = q64 + ((size_t)bh * NN + qn) * DH;
    const double* kb = k64 + (size_t)bh * NN * DH;
    const double qd = qrow[lane];
    double myS = -1.0e300;
#pragma unroll 1
    for (int t = 0; t < 20; ++t) {
        int jt = __shfl(cand, t);
        double pr = qd * kb[(size_t)jt * DH + lane];
#pragma unroll
        for (int off = 32; off; off >>= 1) pr += __shfl_xor(pr, off);
        if (lane == t) myS = pr * 0.125;
    }

    // exact fp64 top-16 among the 20 (tie -> lower index); rank t lands on lane t
    double sS = (lane < 20) ? myS : -1.0e300;
    int sI = (lane < 20) ? cand : (1 << 30);
    double selS = 0.0; int selIdx = 0;
#pragma unroll 1
    for (int t = 0; t < KTOP; ++t) {
        double bv = sS; int bi = sI;
#pragma unroll
        for (int off = 32; off; off >>= 1) {
            double ov = __shfl_xor(bv, off);
            int oi = __shfl_xor(bi, off);
            if (ov > bv || (ov == bv && oi < bi)) { bv = ov; bi = oi; }
        }
        if (lane == t) { selS = bv; selIdx = bi; }
        if (sI == bi) sS = -1.0e300;
    }

    // probs: softmax over the 16 selected (full-softmax denom cancels; clip inert)
    double m = __shfl(selS, 0);
    float e = (lane < KTOP) ? expf((float)(selS - m)) : 0.0f;
    float sum = e;
#pragma unroll
    for (int off = 32; off; off >>= 1) sum += __shfl_xor(sum, off);
    float p = e / sum;

    // AV: o[d] = sum_t p_t * v[sel_t][d]  (lane <-> d)
    const float* vb = v32 + (size_t)bh * NN * DH;
    float o = 0.0f;
#pragma unroll
    for (int t = 0; t < KTOP; ++t) {
        int jt = __shfl(selIdx, t);
        float pt = __shfl(p, t);
        o = fmaf(pt, vb[(size_t)jt * DH + lane], o);
    }

    // rewrite attn row: zeros, drain stores, then scatter 16 probs
#pragma unroll
    for (int i = 0; i < 4; ++i) {
        float4 z = make_float4(0.f, 0.f, 0.f, 0.f);
        *(float4*)&srow[i * 256 + lane * 4] = z;
    }
    asm volatile("s_waitcnt vmcnt(0)" ::: "memory");
    if (lane < KTOP) srow[selIdx] = p;

    int b = bh / HH, h = bh - b * HH;
    xatt[((size_t)b * NN + qn) * CC + h * DH + lane] = o;
}

// ---------------- Kernel 3: output projection (unchanged) ----------------
__global__ __launch_bounds__(256) void out_proj(
    const float* __restrict__ a, const float* __restrict__ w,
    const float* __restrict__ bias, float* __restrict__ out) {
    __shared__ float a_lds[64][17];
    __shared__ float b_lds[64][17];
    const int tid = threadIdx.x;
    const int m0 = blockIdx.x * 64, n0 = blockIdx.y * 64;
    const int ty = tid >> 4, tx = tid & 15;
    const int lr = tid >> 2, lc = (tid & 3) << 2;

    double acc[4][4];
#pragma unroll
    for (int i = 0; i < 4; ++i)
#pragma unroll
        for (int j = 0; j < 4; ++j) acc[i][j] = 0.0;

    for (int k0 = 0; k0 < CC; k0 += 16) {
        float4 av = *reinterpret_cast<const float4*>(&a[(size_t)(m0 + lr) * CC + k0 + lc]);
        float4 wv = *reinterpret_cast<const float4*>(&w[(size_t)(n0 + lr) * CC + k0 + lc]);
        __syncthreads();
        a_lds[lr][lc + 0] = av.x; a_lds[lr][lc + 1] = av.y;
        a_lds[lr][lc + 2] = av.z; a_lds[lr][lc + 3] = av.w;
        b_lds[lr][lc + 0] = wv.x; b_lds[lr][lc + 1] = wv.y;
        b_lds[lr][lc + 2] = wv.z; b_lds[lr][lc + 3] = wv.w;
        __syncthreads();
#pragma unroll
        for (int kk = 0; kk < 16; ++kk) {
            double a0 = (double)a_lds[ty + 0][kk];
            double a1 = (double)a_lds[ty + 16][kk];
            double a2 = (double)a_lds[ty + 32][kk];
            double a3 = (double)a_lds[ty + 48][kk];
            double w0 = (double)b_lds[tx + 0][kk];
            double w1 = (double)b_lds[tx + 16][kk];
            double w2 = (double)b_lds[tx + 32][kk];
            double w3 = (double)b_lds[tx + 48][kk];
            acc[0][0] = fma(a0, w0, acc[0][0]); acc[0][1] = fma(a0, w1, acc[0][1]);
            acc[0][2] = fma(a0, w2, acc[0][2]); acc[0][3] = fma(a0, w3, acc[0][3]);
            acc[1][0] = fma(a1, w0, acc[1][0]); acc[1][1] = fma(a1, w1, acc[1][1]);
            acc[1][2] = fma(a1, w2, acc[1][2]); acc[1][3] = fma(a1, w3, acc[1][3]);
            acc[2][0] = fma(a2, w0, acc[2][0]); acc[2][1] = fma(a2, w1, acc[2][1]);
            acc[2][2] = fma(a2, w2, acc[2][2]); acc[2][3] = fma(a2, w3, acc[2][3]);
            acc[3][0] = fma(a3, w0, acc[3][0]); acc[3][1] = fma(a3, w1, acc[3][1]);
            acc[3][2] = fma(a3, w2, acc[3][2]); acc[3][3] = fma(a3, w3, acc[3][3]);
        }
    }

#pragma unroll
    for (int i = 0; i < 4; ++i) {
#pragma unroll
        for (int j = 0; j < 4; ++j) {
            int m = m0 + ty + i * 16;
            int n = n0 + tx + j * 16;
            out[(size_t)m * CC + n] = (float)(acc[i][j] + (double)bias[n]);
        }
    }
}

extern "C" void kernel_launch(void* const* d_in, const int* in_sizes, int n_in,
                              void* d_out, int out_size, void* d_ws, size_t ws_size,
                              hipStream_t stream) {
    const float* x     = (const float*)d_in[0];
    const float* w_in  = (const float*)d_in[1];
    const float* b_in  = (const float*)d_in[2];
    const float* w_out = (const float*)d_in[3];
    const float* b_out = (const float*)d_in[4];

    float* xout     = (float*)d_out;                        // [B][N][C]
    float* attn_out = (float*)d_out + (size_t)BB * NN * CC; // [B][H][N][N]

    char* ws = (char*)d_ws;
    double* qws  = (double*)ws;                                   // 25,165,824 B
    double* kws  = (double*)(ws + 25165824);                      // 25,165,824 B
    float*  vws  = (float*)(ws + 50331648);                       // 12,582,912 B
    float*  xatt = (float*)(ws + 62914560);                       // 12,582,912 B

    hipLaunchKernelGGL(qkv_proj, dim3(64, 36), dim3(256), 0, stream,
                       x, w_in, b_in, qws, kws, vws);
    hipLaunchKernelGGL(scores32, dim3(NN / 128, BB * HH), dim3(256), 0, stream,
                       qws, kws, attn_out);
    hipLaunchKernelGGL(topk_select, dim3(BB * HH * (NN / 4)), dim3(256), 0, stream,
                       qws, kws, vws, attn_out, xatt);
    hipLaunchKernelGGL(out_proj, dim3(64, 12), dim3(256), 0, stream,
                       xatt, w_out, b_out, xout);
}

// Round 3
// 1062.734 us; speedup vs baseline: 1.8468x; 1.0297x over previous
//
#include <hip/hip_runtime.h>
#include <math.h>
#include <stdint.h>

#define BB 4
#define NN 1024
#define CC 768
#define HH 12
#define DH 64
#define KTOP 16

// ---------------- Kernel 1a: Q/K projection (fp64 accumulate, ranking-critical) ------------
__global__ __launch_bounds__(256) void qk_proj(
    const float* __restrict__ x, const float* __restrict__ w,
    const float* __restrict__ bias,
    double* __restrict__ qws, double* __restrict__ kws) {
    __shared__ float a_lds[64][17];
    __shared__ float b_lds[64][17];
    const int tid = threadIdx.x;
    const int m0 = blockIdx.x * 64, n0 = blockIdx.y * 64;   // n0 in [0,1536)
    const int ty = tid >> 4, tx = tid & 15;
    const int lr = tid >> 2, lc = (tid & 3) << 2;

    double acc[4][4];
#pragma unroll
    for (int i = 0; i < 4; ++i)
#pragma unroll
        for (int j = 0; j < 4; ++j) acc[i][j] = 0.0;

    for (int k0 = 0; k0 < CC; k0 += 16) {
        float4 av = *reinterpret_cast<const float4*>(&x[(size_t)(m0 + lr) * CC + k0 + lc]);
        float4 wv = *reinterpret_cast<const float4*>(&w[(size_t)(n0 + lr) * CC + k0 + lc]);
        __syncthreads();
        a_lds[lr][lc + 0] = av.x; a_lds[lr][lc + 1] = av.y;
        a_lds[lr][lc + 2] = av.z; a_lds[lr][lc + 3] = av.w;
        b_lds[lr][lc + 0] = wv.x; b_lds[lr][lc + 1] = wv.y;
        b_lds[lr][lc + 2] = wv.z; b_lds[lr][lc + 3] = wv.w;
        __syncthreads();
#pragma unroll
        for (int kk = 0; kk < 16; ++kk) {
            double a0 = (double)a_lds[ty + 0][kk];
            double a1 = (double)a_lds[ty + 16][kk];
            double a2 = (double)a_lds[ty + 32][kk];
            double a3 = (double)a_lds[ty + 48][kk];
            double w0 = (double)b_lds[tx + 0][kk];
            double w1 = (double)b_lds[tx + 16][kk];
            double w2 = (double)b_lds[tx + 32][kk];
            double w3 = (double)b_lds[tx + 48][kk];
            acc[0][0] = fma(a0, w0, acc[0][0]); acc[0][1] = fma(a0, w1, acc[0][1]);
            acc[0][2] = fma(a0, w2, acc[0][2]); acc[0][3] = fma(a0, w3, acc[0][3]);
            acc[1][0] = fma(a1, w0, acc[1][0]); acc[1][1] = fma(a1, w1, acc[1][1]);
            acc[1][2] = fma(a1, w2, acc[1][2]); acc[1][3] = fma(a1, w3, acc[1][3]);
            acc[2][0] = fma(a2, w0, acc[2][0]); acc[2][1] = fma(a2, w1, acc[2][1]);
            acc[2][2] = fma(a2, w2, acc[2][2]); acc[2][3] = fma(a2, w3, acc[2][3]);
            acc[3][0] = fma(a3, w0, acc[3][0]); acc[3][1] = fma(a3, w1, acc[3][1]);
            acc[3][2] = fma(a3, w2, acc[3][2]); acc[3][3] = fma(a3, w3, acc[3][3]);
        }
    }

#pragma unroll
    for (int i = 0; i < 4; ++i) {
#pragma unroll
        for (int j = 0; j < 4; ++j) {
            int m = m0 + ty + i * 16;
            int col = n0 + tx + j * 16;
            double val = acc[i][j] + (double)bias[col];
            int t = (col >= CC);
            int rem = col - (t ? CC : 0);
            int h = rem >> 6, d = rem & 63;
            int b = m >> 10, n = m & 1023;
            size_t off = (((size_t)(b * HH + h)) * NN + n) * DH + d;
            if (t == 0) qws[off] = val;
            else kws[off] = val;
        }
    }
}

// ---------------- Kernel 1b: V projection (fp32 — rank-insensitive) ----------------
__global__ __launch_bounds__(256) void v_proj(
    const float* __restrict__ x, const float* __restrict__ w,
    const float* __restrict__ bias, float* __restrict__ vws) {
    __shared__ float a_lds[64][17];
    __shared__ float b_lds[64][17];
    const int tid = threadIdx.x;
    const int m0 = blockIdx.x * 64, n0 = blockIdx.y * 64;   // n0 in [0,768)
    const int ty = tid >> 4, tx = tid & 15;
    const int lr = tid >> 2, lc = (tid & 3) << 2;

    float acc[4][4];
#pragma unroll
    for (int i = 0; i < 4; ++i)
#pragma unroll
        for (int j = 0; j < 4; ++j) acc[i][j] = 0.0f;

    for (int k0 = 0; k0 < CC; k0 += 16) {
        float4 av = *reinterpret_cast<const float4*>(&x[(size_t)(m0 + lr) * CC + k0 + lc]);
        float4 wv = *reinterpret_cast<const float4*>(&w[(size_t)(1536 + n0 + lr) * CC + k0 + lc]);
        __syncthreads();
        a_lds[lr][lc + 0] = av.x; a_lds[lr][lc + 1] = av.y;
        a_lds[lr][lc + 2] = av.z; a_lds[lr][lc + 3] = av.w;
        b_lds[lr][lc + 0] = wv.x; b_lds[lr][lc + 1] = wv.y;
        b_lds[lr][lc + 2] = wv.z; b_lds[lr][lc + 3] = wv.w;
        __syncthreads();
#pragma unroll
        for (int kk = 0; kk < 16; ++kk) {
            float a0 = a_lds[ty + 0][kk];
            float a1 = a_lds[ty + 16][kk];
            float a2 = a_lds[ty + 32][kk];
            float a3 = a_lds[ty + 48][kk];
            float w0 = b_lds[tx + 0][kk];
            float w1 = b_lds[tx + 16][kk];
            float w2 = b_lds[tx + 32][kk];
            float w3 = b_lds[tx + 48][kk];
            acc[0][0] = fmaf(a0, w0, acc[0][0]); acc[0][1] = fmaf(a0, w1, acc[0][1]);
            acc[0][2] = fmaf(a0, w2, acc[0][2]); acc[0][3] = fmaf(a0, w3, acc[0][3]);
            acc[1][0] = fmaf(a1, w0, acc[1][0]); acc[1][1] = fmaf(a1, w1, acc[1][1]);
            acc[1][2] = fmaf(a1, w2, acc[1][2]); acc[1][3] = fmaf(a1, w3, acc[1][3]);
            acc[2][0] = fmaf(a2, w0, acc[2][0]); acc[2][1] = fmaf(a2, w1, acc[2][1]);
            acc[2][2] = fmaf(a2, w2, acc[2][2]); acc[2][3] = fmaf(a2, w3, acc[2][3]);
            acc[3][0] = fmaf(a3, w0, acc[3][0]); acc[3][1] = fmaf(a3, w1, acc[3][1]);
            acc[3][2] = fmaf(a3, w2, acc[3][2]); acc[3][3] = fmaf(a3, w3, acc[3][3]);
        }
    }

#pragma unroll
    for (int i = 0; i < 4; ++i) {
#pragma unroll
        for (int j = 0; j < 4; ++j) {
            int m = m0 + ty + i * 16;
            int col = n0 + tx + j * 16;              // [0,768)
            float val = acc[i][j] + bias[1536 + col];
            int h = col >> 6, d = col & 63;
            int b = m >> 10, n = m & 1023;
            vws[(((size_t)(b * HH + h)) * NN + n) * DH + d] = val;
        }
    }
}

// ---------------- Kernel 2a: fp32 scores GEMM -> raw scores into attn region ----------------
__global__ __launch_bounds__(256) void scores32(
    const double* __restrict__ q64, const double* __restrict__ k64,
    float* __restrict__ attn_out) {
    __shared__ float qs[128][64];
    __shared__ float ks[128][64];
    const int bh = blockIdx.y;
    const int m0 = blockIdx.x * 128;
    const int tid = threadIdx.x;
    const int ty = tid >> 4, tx = tid & 15;

    const double* qb = q64 + ((size_t)bh * NN + m0) * DH;
    const double* kb = k64 + (size_t)bh * NN * DH;

#pragma unroll
    for (int wv = 0; wv < 8; ++wv) {
        int e = tid + 256 * wv;
        int row = e >> 4, d4 = e & 15;
        const double* src = qb + (size_t)row * DH + d4 * 4;
        float4 f;
        f.x = (float)(src[0] * 0.125); f.y = (float)(src[1] * 0.125);
        f.z = (float)(src[2] * 0.125); f.w = (float)(src[3] * 0.125);
        ((float4*)qs[row])[d4 ^ ((row >> 3) & 15)] = f;
    }

    float* orow0 = attn_out + ((size_t)bh * NN + m0) * NN;

    for (int c0 = 0; c0 < NN; c0 += 128) {
        __syncthreads();
#pragma unroll
        for (int wv = 0; wv < 8; ++wv) {
            int e = tid + 256 * wv;
            int col = e >> 4, d4 = e & 15;
            const double* src = kb + (size_t)(c0 + col) * DH + d4 * 4;
            float4 f;
            f.x = (float)src[0]; f.y = (float)src[1];
            f.z = (float)src[2]; f.w = (float)src[3];
            ((float4*)ks[col])[d4 ^ ((col >> 3) & 15)] = f;
        }
        __syncthreads();

        float acc[8][8];
#pragma unroll
        for (int i = 0; i < 8; ++i)
#pragma unroll
            for (int j = 0; j < 8; ++j) acc[i][j] = 0.0f;

#pragma unroll
        for (int d4 = 0; d4 < 16; ++d4) {
            float4 a4[8];
#pragma unroll
            for (int i = 0; i < 8; ++i)
                a4[i] = ((float4*)qs[8 * ty + i])[d4 ^ ty];
#pragma unroll
            for (int j = 0; j < 8; ++j) {
                float4 b4 = ((float4*)ks[8 * tx + j])[d4 ^ tx];
#pragma unroll
                for (int i = 0; i < 8; ++i) {
                    acc[i][j] = fmaf(a4[i].x, b4.x, acc[i][j]);
                    acc[i][j] = fmaf(a4[i].y, b4.y, acc[i][j]);
                    acc[i][j] = fmaf(a4[i].z, b4.z, acc[i][j]);
                    acc[i][j] = fmaf(a4[i].w, b4.w, acc[i][j]);
                }
            }
        }

#pragma unroll
        for (int i = 0; i < 8; ++i) {
#pragma unroll
            for (int jj = 0; jj < 2; ++jj) {
                float4 o;
                o.x = acc[i][4 * jj + 0]; o.y = acc[i][4 * jj + 1];
                o.z = acc[i][4 * jj + 2]; o.w = acc[i][4 * jj + 3];
                *(float4*)&orow0[(size_t)(8 * ty + i) * NN + c0 + 8 * tx + 4 * jj] = o;
            }
        }
    }
}

// ---------------- Kernel 2b: radix-threshold candidates -> fp64 exact top-16 + AV ----------
__global__ __launch_bounds__(256) void topk_select(
    const double* __restrict__ q64, const double* __restrict__ k64,
    const float* __restrict__ v32,
    float* __restrict__ attn_out, float* __restrict__ xatt) {
    __shared__ int cand_lds[4][64];
    const int blk = blockIdx.x;
    const int wave = threadIdx.x >> 6, lane = threadIdx.x & 63;
    const int bh = blk >> 8;
    const int qn = ((blk & 255) << 2) | wave;

    float* srow = attn_out + ((size_t)bh * NN + qn) * NN;

    // load 16 scores, transform to order-preserving sortable uint
    uint32_t su[16];
#pragma unroll
    for (int i = 0; i < 4; ++i) {
        float4 t = *(const float4*)&srow[i * 256 + lane * 4];
        float f[4] = {t.x, t.y, t.z, t.w};
#pragma unroll
        for (int k2 = 0; k2 < 4; ++k2) {
            uint32_t u = __float_as_uint(f[k2]);
            su[4 * i + k2] = u ^ ((u & 0x80000000u) ? 0xFFFFFFFFu : 0x80000000u);
        }
    }

    // binary search MSB->LSB: largest thr with count(su >= thr) >= 20;
    // early-exit once count lands in [20, 64].
    uint32_t thr = 0;
    for (int b = 31; b >= 0; --b) {
        uint32_t test = thr | (1u << b);
        int cnt = 0;
#pragma unroll
        for (int r = 0; r < 16; ++r)
            cnt += __popcll(__ballot(su[r] >= test));
        if (cnt >= 20) {
            thr = test;
            if (cnt <= 64) break;
        }
    }

    // compact candidate column indices into LDS (column order)
    int C = 0;
#pragma unroll
    for (int r = 0; r < 16; ++r) {
        bool p = (su[r] >= thr);
        unsigned long long mask = __ballot(p);
        if (p) {
            int pos = C + __popcll(mask & ((1ull << lane) - 1ull));
            if (pos < 64) cand_lds[wave][pos] = ((r >> 2) << 8) + (lane << 2) + (r & 3);
        }
        C += __popcll(mask);
    }
    if (C > 64) C = 64;
    int cand = cand_lds[wave][lane < C ? lane : 0];

    // fp64 rescore of the C candidates (lane <-> d, coalesced 512B k-row loads)
    const double qd = q64[((size_t)bh * NN + qn) * DH + lane];
    const double* kb = k64 + (size_t)bh * NN * DH;
    double myS = -1.0e300;
    int myI = (1 << 30);
#pragma unroll 1
    for (int t = 0; t < C; ++t) {
        int jt = __shfl(cand, t);
        double pr = qd * kb[(size_t)jt * DH + lane];
#pragma unroll
        for (int off = 32; off; off >>= 1) pr += __shfl_xor(pr, off);
        if (lane == t) { myS = pr * 0.125; myI = jt; }
    }

    // exact fp64 top-16 among C (tie -> lower index); rank t lands on lane t
    double sS = myS;
    int sI = myI;
    double selS = 0.0; int selIdx = 0;
#pragma unroll 1
    for (int t = 0; t < KTOP; ++t) {
        double bv = sS; int bi = sI;
#pragma unroll
        for (int off = 32; off; off >>= 1) {
            double ov = __shfl_xor(bv, off);
            int oi = __shfl_xor(bi, off);
            if (ov > bv || (ov == bv && oi < bi)) { bv = ov; bi = oi; }
        }
        if (lane == t) { selS = bv; selIdx = bi; }
        if (sI == bi) sS = -1.0e300;
    }

    // probs: softmax over the 16 selected (full-softmax denom cancels; clip inert)
    double m = __shfl(selS, 0);
    float e = (lane < KTOP) ? expf((float)(selS - m)) : 0.0f;
    float sum = e;
#pragma unroll
    for (int off = 32; off; off >>= 1) sum += __shfl_xor(sum, off);
    float p = e / sum;

    // AV: o[d] = sum_t p_t * v[sel_t][d]  (lane <-> d)
    const float* vb = v32 + (size_t)bh * NN * DH;
    float o = 0.0f;
#pragma unroll
    for (int t = 0; t < KTOP; ++t) {
        int jt = __shfl(selIdx, t);
        float pt = __shfl(p, t);
        o = fmaf(pt, vb[(size_t)jt * DH + lane], o);
    }

    // rewrite attn row: zeros, drain stores, then scatter 16 probs
#pragma unroll
    for (int i = 0; i < 4; ++i) {
        float4 z = make_float4(0.f, 0.f, 0.f, 0.f);
        *(float4*)&srow[i * 256 + lane * 4] = z;
    }
    asm volatile("s_waitcnt vmcnt(0)" ::: "memory");
    if (lane < KTOP) srow[selIdx] = p;

    int b = bh / HH, h = bh - b * HH;
    xatt[((size_t)b * NN + qn) * CC + h * DH + lane] = o;
}

// ---------------- Kernel 3: output projection (fp32) ----------------
__global__ __launch_bounds__(256) void out_proj(
    const float* __restrict__ a, const float* __restrict__ w,
    const float* __restrict__ bias, float* __restrict__ out) {
    __shared__ float a_lds[64][17];
    __shared__ float b_lds[64][17];
    const int tid = threadIdx.x;
    const int m0 = blockIdx.x * 64, n0 = blockIdx.y * 64;
    const int ty = tid >> 4, tx = tid & 15;
    const int lr = tid >> 2, lc = (tid & 3) << 2;

    float acc[4][4];
#pragma unroll
    for (int i = 0; i < 4; ++i)
#pragma unroll
        for (int j = 0; j < 4; ++j) acc[i][j] = 0.0f;

    for (int k0 = 0; k0 < CC; k0 += 16) {
        float4 av = *reinterpret_cast<const float4*>(&a[(size_t)(m0 + lr) * CC + k0 + lc]);
        float4 wv = *reinterpret_cast<const float4*>(&w[(size_t)(n0 + lr) * CC + k0 + lc]);
        __syncthreads();
        a_lds[lr][lc + 0] = av.x; a_lds[lr][lc + 1] = av.y;
        a_lds[lr][lc + 2] = av.z; a_lds[lr][lc + 3] = av.w;
        b_lds[lr][lc + 0] = wv.x; b_lds[lr][lc + 1] = wv.y;
        b_lds[lr][lc + 2] = wv.z; b_lds[lr][lc + 3] = wv.w;
        __syncthreads();
#pragma unroll
        for (int kk = 0; kk < 16; ++kk) {
            float a0 = a_lds[ty + 0][kk];
            float a1 = a_lds[ty + 16][kk];
            float a2 = a_lds[ty + 32][kk];
            float a3 = a_lds[ty + 48][kk];
            float w0 = b_lds[tx + 0][kk];
            float w1 = b_lds[tx + 16][kk];
            float w2 = b_lds[tx + 32][kk];
            float w3 = b_lds[tx + 48][kk];
            acc[0][0] = fmaf(a0, w0, acc[0][0]); acc[0][1] = fmaf(a0, w1, acc[0][1]);
            acc[0][2] = fmaf(a0, w2, acc[0][2]); acc[0][3] = fmaf(a0, w3, acc[0][3]);
            acc[1][0] = fmaf(a1, w0, acc[1][0]); acc[1][1] = fmaf(a1, w1, acc[1][1]);
            acc[1][2] = fmaf(a1, w2, acc[1][2]); acc[1][3] = fmaf(a1, w3, acc[1][3]);
            acc[2][0] = fmaf(a2, w0, acc[2][0]); acc[2][1] = fmaf(a2, w1, acc[2][1]);
            acc[2][2] = fmaf(a2, w2, acc[2][2]); acc[2][3] = fmaf(a2, w3, acc[2][3]);
            acc[3][0] = fmaf(a3, w0, acc[3][0]); acc[3][1] = fmaf(a3, w1, acc[3][1]);
            acc[3][2] = fmaf(a3, w2, acc[3][2]); acc[3][3] = fmaf(a3, w3, acc[3][3]);
        }
    }

#pragma unroll
    for (int i = 0; i < 4; ++i) {
#pragma unroll
        for (int j = 0; j < 4; ++j) {
            int m = m0 + ty + i * 16;
            int n = n0 + tx + j * 16;
            out[(size_t)m * CC + n] = acc[i][j] + bias[n];
        }
    }
}

extern "C" void kernel_launch(void* const* d_in, const int* in_sizes, int n_in,
                              void* d_out, int out_size, void* d_ws, size_t ws_size,
                              hipStream_t stream) {
    const float* x     = (const float*)d_in[0];
    const float* w_in  = (const float*)d_in[1];
    const float* b_in  = (const float*)d_in[2];
    const float* w_out = (const float*)d_in[3];
    const float* b_out = (const float*)d_in[4];

    float* xout     = (float*)d_out;                        // [B][N][C]
    float* attn_out = (float*)d_out + (size_t)BB * NN * CC; // [B][H][N][N]

    char* ws = (char*)d_ws;
    double* qws  = (double*)ws;                                   // 25,165,824 B
    double* kws  = (double*)(ws + 25165824);                      // 25,165,824 B
    float*  vws  = (float*)(ws + 50331648);                       // 12,582,912 B
    float*  xatt = (float*)(ws + 62914560);                       // 12,582,912 B

    hipLaunchKernelGGL(qk_proj, dim3(64, 24), dim3(256), 0, stream,
                       x, w_in, b_in, qws, kws);
    hipLaunchKernelGGL(v_proj, dim3(64, 12), dim3(256), 0, stream,
                       x, w_in, b_in, vws);
    hipLaunchKernelGGL(scores32, dim3(NN / 128, BB * HH), dim3(256), 0, stream,
                       qws, kws, attn_out);
    hipLaunchKernelGGL(topk_select, dim3(BB * HH * (NN / 4)), dim3(256), 0, stream,
                       qws, kws, vws, attn_out, xatt);
    hipLaunchKernelGGL(out_proj, dim3(64, 12), dim3(256), 0, stream,
                       xatt, w_out, b_out, xout);
}

// Round 4
// 699.641 us; speedup vs baseline: 2.8052x; 1.5190x over previous
//
#include <hip/hip_runtime.h>
#include <math.h>
#include <stdint.h>

#define BB 4
#define NN 1024
#define CC 768
#define HH 12
#define DH 64
#define KTOP 16

// ---------------- Kernel 1a: Q/K projection (fp64 accumulate, ranking-critical) ------------
__global__ __launch_bounds__(256) void qk_proj(
    const float* __restrict__ x, const float* __restrict__ w,
    const float* __restrict__ bias,
    double* __restrict__ qws, double* __restrict__ kws) {
    __shared__ float a_lds[64][17];
    __shared__ float b_lds[64][17];
    const int tid = threadIdx.x;
    const int m0 = blockIdx.x * 64, n0 = blockIdx.y * 64;   // n0 in [0,1536)
    const int ty = tid >> 4, tx = tid & 15;
    const int lr = tid >> 2, lc = (tid & 3) << 2;

    double acc[4][4];
#pragma unroll
    for (int i = 0; i < 4; ++i)
#pragma unroll
        for (int j = 0; j < 4; ++j) acc[i][j] = 0.0;

    for (int k0 = 0; k0 < CC; k0 += 16) {
        float4 av = *reinterpret_cast<const float4*>(&x[(size_t)(m0 + lr) * CC + k0 + lc]);
        float4 wv = *reinterpret_cast<const float4*>(&w[(size_t)(n0 + lr) * CC + k0 + lc]);
        __syncthreads();
        a_lds[lr][lc + 0] = av.x; a_lds[lr][lc + 1] = av.y;
        a_lds[lr][lc + 2] = av.z; a_lds[lr][lc + 3] = av.w;
        b_lds[lr][lc + 0] = wv.x; b_lds[lr][lc + 1] = wv.y;
        b_lds[lr][lc + 2] = wv.z; b_lds[lr][lc + 3] = wv.w;
        __syncthreads();
#pragma unroll
        for (int kk = 0; kk < 16; ++kk) {
            double a0 = (double)a_lds[ty + 0][kk];
            double a1 = (double)a_lds[ty + 16][kk];
            double a2 = (double)a_lds[ty + 32][kk];
            double a3 = (double)a_lds[ty + 48][kk];
            double w0 = (double)b_lds[tx + 0][kk];
            double w1 = (double)b_lds[tx + 16][kk];
            double w2 = (double)b_lds[tx + 32][kk];
            double w3 = (double)b_lds[tx + 48][kk];
            acc[0][0] = fma(a0, w0, acc[0][0]); acc[0][1] = fma(a0, w1, acc[0][1]);
            acc[0][2] = fma(a0, w2, acc[0][2]); acc[0][3] = fma(a0, w3, acc[0][3]);
            acc[1][0] = fma(a1, w0, acc[1][0]); acc[1][1] = fma(a1, w1, acc[1][1]);
            acc[1][2] = fma(a1, w2, acc[1][2]); acc[1][3] = fma(a1, w3, acc[1][3]);
            acc[2][0] = fma(a2, w0, acc[2][0]); acc[2][1] = fma(a2, w1, acc[2][1]);
            acc[2][2] = fma(a2, w2, acc[2][2]); acc[2][3] = fma(a2, w3, acc[2][3]);
            acc[3][0] = fma(a3, w0, acc[3][0]); acc[3][1] = fma(a3, w1, acc[3][1]);
            acc[3][2] = fma(a3, w2, acc[3][2]); acc[3][3] = fma(a3, w3, acc[3][3]);
        }
    }

#pragma unroll
    for (int i = 0; i < 4; ++i) {
#pragma unroll
        for (int j = 0; j < 4; ++j) {
            int m = m0 + ty + i * 16;
            int col = n0 + tx + j * 16;
            double val = acc[i][j] + (double)bias[col];
            int t = (col >= CC);
            int rem = col - (t ? CC : 0);
            int h = rem >> 6, d = rem & 63;
            int b = m >> 10, n = m & 1023;
            size_t off = (((size_t)(b * HH + h)) * NN + n) * DH + d;
            if (t == 0) qws[off] = val;
            else kws[off] = val;
        }
    }
}

// ---------------- Kernel 1b: V projection (fp32 — rank-insensitive) ----------------
__global__ __launch_bounds__(256) void v_proj(
    const float* __restrict__ x, const float* __restrict__ w,
    const float* __restrict__ bias, float* __restrict__ vws) {
    __shared__ float a_lds[64][17];
    __shared__ float b_lds[64][17];
    const int tid = threadIdx.x;
    const int m0 = blockIdx.x * 64, n0 = blockIdx.y * 64;   // n0 in [0,768)
    const int ty = tid >> 4, tx = tid & 15;
    const int lr = tid >> 2, lc = (tid & 3) << 2;

    float acc[4][4];
#pragma unroll
    for (int i = 0; i < 4; ++i)
#pragma unroll
        for (int j = 0; j < 4; ++j) acc[i][j] = 0.0f;

    for (int k0 = 0; k0 < CC; k0 += 16) {
        float4 av = *reinterpret_cast<const float4*>(&x[(size_t)(m0 + lr) * CC + k0 + lc]);
        float4 wv = *reinterpret_cast<const float4*>(&w[(size_t)(1536 + n0 + lr) * CC + k0 + lc]);
        __syncthreads();
        a_lds[lr][lc + 0] = av.x; a_lds[lr][lc + 1] = av.y;
        a_lds[lr][lc + 2] = av.z; a_lds[lr][lc + 3] = av.w;
        b_lds[lr][lc + 0] = wv.x; b_lds[lr][lc + 1] = wv.y;
        b_lds[lr][lc + 2] = wv.z; b_lds[lr][lc + 3] = wv.w;
        __syncthreads();
#pragma unroll
        for (int kk = 0; kk < 16; ++kk) {
            float a0 = a_lds[ty + 0][kk];
            float a1 = a_lds[ty + 16][kk];
            float a2 = a_lds[ty + 32][kk];
            float a3 = a_lds[ty + 48][kk];
            float w0 = b_lds[tx + 0][kk];
            float w1 = b_lds[tx + 16][kk];
            float w2 = b_lds[tx + 32][kk];
            float w3 = b_lds[tx + 48][kk];
            acc[0][0] = fmaf(a0, w0, acc[0][0]); acc[0][1] = fmaf(a0, w1, acc[0][1]);
            acc[0][2] = fmaf(a0, w2, acc[0][2]); acc[0][3] = fmaf(a0, w3, acc[0][3]);
            acc[1][0] = fmaf(a1, w0, acc[1][0]); acc[1][1] = fmaf(a1, w1, acc[1][1]);
            acc[1][2] = fmaf(a1, w2, acc[1][2]); acc[1][3] = fmaf(a1, w3, acc[1][3]);
            acc[2][0] = fmaf(a2, w0, acc[2][0]); acc[2][1] = fmaf(a2, w1, acc[2][1]);
            acc[2][2] = fmaf(a2, w2, acc[2][2]); acc[2][3] = fmaf(a2, w3, acc[2][3]);
            acc[3][0] = fmaf(a3, w0, acc[3][0]); acc[3][1] = fmaf(a3, w1, acc[3][1]);
            acc[3][2] = fmaf(a3, w2, acc[3][2]); acc[3][3] = fmaf(a3, w3, acc[3][3]);
        }
    }

#pragma unroll
    for (int i = 0; i < 4; ++i) {
#pragma unroll
        for (int j = 0; j < 4; ++j) {
            int m = m0 + ty + i * 16;
            int col = n0 + tx + j * 16;              // [0,768)
            float val = acc[i][j] + bias[1536 + col];
            int h = col >> 6, d = col & 63;
            int b = m >> 10, n = m & 1023;
            vws[(((size_t)(b * HH + h)) * NN + n) * DH + d] = val;
        }
    }
}

// ---------------- Kernel 2a: fp32 scores GEMM -> raw scores into attn region ----------------
__global__ __launch_bounds__(256) void scores32(
    const double* __restrict__ q64, const double* __restrict__ k64,
    float* __restrict__ attn_out) {
    __shared__ float qs[128][64];
    __shared__ float ks[128][64];
    const int bh = blockIdx.y;
    const int m0 = blockIdx.x * 128;
    const int tid = threadIdx.x;
    const int ty = tid >> 4, tx = tid & 15;

    const double* qb = q64 + ((size_t)bh * NN + m0) * DH;
    const double* kb = k64 + (size_t)bh * NN * DH;

#pragma unroll
    for (int wv = 0; wv < 8; ++wv) {
        int e = tid + 256 * wv;
        int row = e >> 4, d4 = e & 15;
        const double* src = qb + (size_t)row * DH + d4 * 4;
        float4 f;
        f.x = (float)(src[0] * 0.125); f.y = (float)(src[1] * 0.125);
        f.z = (float)(src[2] * 0.125); f.w = (float)(src[3] * 0.125);
        ((float4*)qs[row])[d4 ^ ((row >> 3) & 15)] = f;
    }

    float* orow0 = attn_out + ((size_t)bh * NN + m0) * NN;

    for (int c0 = 0; c0 < NN; c0 += 128) {
        __syncthreads();
#pragma unroll
        for (int wv = 0; wv < 8; ++wv) {
            int e = tid + 256 * wv;
            int col = e >> 4, d4 = e & 15;
            const double* src = kb + (size_t)(c0 + col) * DH + d4 * 4;
            float4 f;
            f.x = (float)src[0]; f.y = (float)src[1];
            f.z = (float)src[2]; f.w = (float)src[3];
            ((float4*)ks[col])[d4 ^ ((col >> 3) & 15)] = f;
        }
        __syncthreads();

        float acc[8][8];
#pragma unroll
        for (int i = 0; i < 8; ++i)
#pragma unroll
            for (int j = 0; j < 8; ++j) acc[i][j] = 0.0f;

#pragma unroll
        for (int d4 = 0; d4 < 16; ++d4) {
            float4 a4[8];
#pragma unroll
            for (int i = 0; i < 8; ++i)
                a4[i] = ((float4*)qs[8 * ty + i])[d4 ^ ty];
#pragma unroll
            for (int j = 0; j < 8; ++j) {
                float4 b4 = ((float4*)ks[8 * tx + j])[d4 ^ tx];
#pragma unroll
                for (int i = 0; i < 8; ++i) {
                    acc[i][j] = fmaf(a4[i].x, b4.x, acc[i][j]);
                    acc[i][j] = fmaf(a4[i].y, b4.y, acc[i][j]);
                    acc[i][j] = fmaf(a4[i].z, b4.z, acc[i][j]);
                    acc[i][j] = fmaf(a4[i].w, b4.w, acc[i][j]);
                }
            }
        }

#pragma unroll
        for (int i = 0; i < 8; ++i) {
#pragma unroll
            for (int jj = 0; jj < 2; ++jj) {
                float4 o;
                o.x = acc[i][4 * jj + 0]; o.y = acc[i][4 * jj + 1];
                o.z = acc[i][4 * jj + 2]; o.w = acc[i][4 * jj + 3];
                *(float4*)&orow0[(size_t)(8 * ty + i) * NN + c0 + 8 * tx + 4 * jj] = o;
            }
        }
    }
}

// ---------------- Kernel 2b: bitonic top-16 with margin-gated fp64 fallback ----------------
__device__ __forceinline__ uint32_t f2su(float f) {
    uint32_t u = __float_as_uint(f);
    return u ^ ((u & 0x80000000u) ? 0xFFFFFFFFu : 0x80000000u);
}
__device__ __forceinline__ float su2f(uint32_t s) {
    uint32_t u = s ^ ((s & 0x80000000u) ? 0x80000000u : 0xFFFFFFFFu);
    return __uint_as_float(u);
}

__global__ __launch_bounds__(256) void topk_select(
    const double* __restrict__ q64, const double* __restrict__ k64,
    const float* __restrict__ v32,
    float* __restrict__ attn_out, float* __restrict__ xatt) {
    __shared__ int      cand_idx[4][64];
    __shared__ uint32_t cand_val[4][64];
    const int blk = blockIdx.x;
    const int wave = threadIdx.x >> 6, lane = threadIdx.x & 63;
    const int bh = blk >> 8;
    const int qn = ((blk & 255) << 2) | wave;

    float* srow = attn_out + ((size_t)bh * NN + qn) * NN;

    // load 16 scores, transform to order-preserving sortable uint
    uint32_t su[16];
#pragma unroll
    for (int i = 0; i < 4; ++i) {
        float4 t = *(const float4*)&srow[i * 256 + lane * 4];
        su[4 * i + 0] = f2su(t.x); su[4 * i + 1] = f2su(t.y);
        su[4 * i + 2] = f2su(t.z); su[4 * i + 3] = f2su(t.w);
    }

    // binary search MSB->LSB: largest thr with count(su >= thr) >= 17; early-exit in [17,64]
    uint32_t thr = 0;
    for (int b = 31; b >= 0; --b) {
        uint32_t test = thr | (1u << b);
        int cnt = 0;
#pragma unroll
        for (int r = 0; r < 16; ++r)
            cnt += __popcll(__ballot(su[r] >= test));
        if (cnt >= 17) { thr = test; if (cnt <= 64) break; }
    }

    // compact (value, column) candidates into LDS (column order)
    int C = 0;
#pragma unroll
    for (int r = 0; r < 16; ++r) {
        bool pr = (su[r] >= thr);
        unsigned long long mask = __ballot(pr);
        if (pr) {
            int pos = C + __popcll(mask & ((1ull << lane) - 1ull));
            if (pos < 64) {
                cand_idx[wave][pos] = ((r >> 2) << 8) + (lane << 2) + (r & 3);
                cand_val[wave][pos] = su[r];
            }
        }
        C += __popcll(mask);
    }
    if (C > 64) C = 64;

    uint32_t key = (lane < C) ? cand_val[wave][lane] : 0u;
    int      idx = (lane < C) ? cand_idx[wave][lane] : (0x40000000 + lane);

    // bitonic sort 64 lanes: (key desc, idx asc)  — 21 exchange steps
#pragma unroll
    for (int k = 2; k <= 64; k <<= 1) {
#pragma unroll
        for (int j = k >> 1; j > 0; j >>= 1) {
            uint32_t ok = __shfl_xor(key, j);
            int      oi = __shfl_xor(idx, j);
            bool mine_better = (key > ok) || (key == ok && idx < oi);
            bool lower = ((lane & j) == 0);
            bool dir_desc = ((lane & k) == 0);
            bool keep = dir_desc ? (lower ? mine_better : !mine_better)
                                 : (lower ? !mine_better : mine_better);
            if (!keep) { key = ok; idx = oi; }
        }
    }

    float f = su2f(key);                  // valid for lane < C (C >= 17)
    float f15 = __shfl(f, 15);
    float f16 = __shfl(f, 16);

    float p = 0.0f;
    int selIdx = idx;

    if (f15 - f16 > 2e-4f) {
        // ---- fast path: fp32 ordering provably matches fp64 at the 16/17 boundary ----
        float m = __shfl(f, 0);
        float e = (lane < KTOP) ? expf(f - m) : 0.0f;
        float sum = e;
#pragma unroll
        for (int off = 32; off; off >>= 1) sum += __shfl_xor(sum, off);
        p = e / sum;
    } else {
        // ---- slow path (~0.8% of rows): fp64 rescore of all candidates near boundary ----
        // superset threshold: any fp64-top-16 member has fp32 score >= f15 - 2E > f15 - 4e-4
        uint32_t thr2 = f2su(f15 - 4e-4f);
        int C2 = 0;
#pragma unroll
        for (int r = 0; r < 16; ++r) {
            bool pr = (su[r] >= thr2);
            unsigned long long mask = __ballot(pr);
            if (pr) {
                int pos = C2 + __popcll(mask & ((1ull << lane) - 1ull));
                if (pos < 64) cand_idx[wave][pos] = ((r >> 2) << 8) + (lane << 2) + (r & 3);
            }
            C2 += __popcll(mask);
        }
        if (C2 > 64) C2 = 64;
        int cand = cand_idx[wave][lane < C2 ? lane : 0];

        const double qd = q64[((size_t)bh * NN + qn) * DH + lane];
        const double* kb = k64 + (size_t)bh * NN * DH;
        double myS = -1.0e300;
        int myI = (1 << 30);
#pragma unroll 1
        for (int t = 0; t < C2; ++t) {
            int jt = __shfl(cand, t);
            double pr = qd * kb[(size_t)jt * DH + lane];
#pragma unroll
            for (int off = 32; off; off >>= 1) pr += __shfl_xor(pr, off);
            if (lane == t) { myS = pr * 0.125; myI = jt; }
        }

        // exact fp64 top-16 among C2 (tie -> lower index); rank t lands on lane t
        double sS = myS;
        int sI = myI;
        double selS = 0.0;
#pragma unroll 1
        for (int t = 0; t < KTOP; ++t) {
            double bv = sS; int bi = sI;
#pragma unroll
            for (int off = 32; off; off >>= 1) {
                double ov = __shfl_xor(bv, off);
                int oi = __shfl_xor(bi, off);
                if (ov > bv || (ov == bv && oi < bi)) { bv = ov; bi = oi; }
            }
            if (lane == t) { selS = bv; selIdx = bi; }
            if (sI == bi) sS = -1.0e300;
        }

        double m = __shfl(selS, 0);
        float e = (lane < KTOP) ? expf((float)(selS - m)) : 0.0f;
        float sum = e;
#pragma unroll
        for (int off = 32; off; off >>= 1) sum += __shfl_xor(sum, off);
        p = e / sum;
    }

    // ---- shared tail: AV, zero-fill row, scatter probs, write xatt ----
    const float* vb = v32 + (size_t)bh * NN * DH;
    float o = 0.0f;
#pragma unroll
    for (int t = 0; t < KTOP; ++t) {
        int jt = __shfl(selIdx, t);
        float pt = __shfl(p, t);
        o = fmaf(pt, vb[(size_t)jt * DH + lane], o);
    }

#pragma unroll
    for (int i = 0; i < 4; ++i) {
        float4 z = make_float4(0.f, 0.f, 0.f, 0.f);
        *(float4*)&srow[i * 256 + lane * 4] = z;
    }
    asm volatile("s_waitcnt vmcnt(0)" ::: "memory");
    if (lane < KTOP) srow[selIdx] = p;

    int b = bh / HH, h = bh - b * HH;
    xatt[((size_t)b * NN + qn) * CC + h * DH + lane] = o;
}

// ---------------- Kernel 3: output projection (fp32) ----------------
__global__ __launch_bounds__(256) void out_proj(
    const float* __restrict__ a, const float* __restrict__ w,
    const float* __restrict__ bias, float* __restrict__ out) {
    __shared__ float a_lds[64][17];
    __shared__ float b_lds[64][17];
    const int tid = threadIdx.x;
    const int m0 = blockIdx.x * 64, n0 = blockIdx.y * 64;
    const int ty = tid >> 4, tx = tid & 15;
    const int lr = tid >> 2, lc = (tid & 3) << 2;

    float acc[4][4];
#pragma unroll
    for (int i = 0; i < 4; ++i)
#pragma unroll
        for (int j = 0; j < 4; ++j) acc[i][j] = 0.0f;

    for (int k0 = 0; k0 < CC; k0 += 16) {
        float4 av = *reinterpret_cast<const float4*>(&a[(size_t)(m0 + lr) * CC + k0 + lc]);
        float4 wv = *reinterpret_cast<const float4*>(&w[(size_t)(n0 + lr) * CC + k0 + lc]);
        __syncthreads();
        a_lds[lr][lc + 0] = av.x; a_lds[lr][lc + 1] = av.y;
        a_lds[lr][lc + 2] = av.z; a_lds[lr][lc + 3] = av.w;
        b_lds[lr][lc + 0] = wv.x; b_lds[lr][lc + 1] = wv.y;
        b_lds[lr][lc + 2] = wv.z; b_lds[lr][lc + 3] = wv.w;
        __syncthreads();
#pragma unroll
        for (int kk = 0; kk < 16; ++kk) {
            float a0 = a_lds[ty + 0][kk];
            float a1 = a_lds[ty + 16][kk];
            float a2 = a_lds[ty + 32][kk];
            float a3 = a_lds[ty + 48][kk];
            float w0 = b_lds[tx + 0][kk];
            float w1 = b_lds[tx + 16][kk];
            float w2 = b_lds[tx + 32][kk];
            float w3 = b_lds[tx + 48][kk];
            acc[0][0] = fmaf(a0, w0, acc[0][0]); acc[0][1] = fmaf(a0, w1, acc[0][1]);
            acc[0][2] = fmaf(a0, w2, acc[0][2]); acc[0][3] = fmaf(a0, w3, acc[0][3]);
            acc[1][0] = fmaf(a1, w0, acc[1][0]); acc[1][1] = fmaf(a1, w1, acc[1][1]);
            acc[1][2] = fmaf(a1, w2, acc[1][2]); acc[1][3] = fmaf(a1, w3, acc[1][3]);
            acc[2][0] = fmaf(a2, w0, acc[2][0]); acc[2][1] = fmaf(a2, w1, acc[2][1]);
            acc[2][2] = fmaf(a2, w2, acc[2][2]); acc[2][3] = fmaf(a2, w3, acc[2][3]);
            acc[3][0] = fmaf(a3, w0, acc[3][0]); acc[3][1] = fmaf(a3, w1, acc[3][1]);
            acc[3][2] = fmaf(a3, w2, acc[3][2]); acc[3][3] = fmaf(a3, w3, acc[3][3]);
        }
    }

#pragma unroll
    for (int i = 0; i < 4; ++i) {
#pragma unroll
        for (int j = 0; j < 4; ++j) {
            int m = m0 + ty + i * 16;
            int n = n0 + tx + j * 16;
            out[(size_t)m * CC + n] = acc[i][j] + bias[n];
        }
    }
}

extern "C" void kernel_launch(void* const* d_in, const int* in_sizes, int n_in,
                              void* d_out, int out_size, void* d_ws, size_t ws_size,
                              hipStream_t stream) {
    const float* x     = (const float*)d_in[0];
    const float* w_in  = (const float*)d_in[1];
    const float* b_in  = (const float*)d_in[2];
    const float* w_out = (const float*)d_in[3];
    const float* b_out = (const float*)d_in[4];

    float* xout     = (float*)d_out;                        // [B][N][C]
    float* attn_out = (float*)d_out + (size_t)BB * NN * CC; // [B][H][N][N]

    char* ws = (char*)d_ws;
    double* qws  = (double*)ws;                                   // 25,165,824 B
    double* kws  = (double*)(ws + 25165824);                      // 25,165,824 B
    float*  vws  = (float*)(ws + 50331648);                       // 12,582,912 B
    float*  xatt = (float*)(ws + 62914560);                       // 12,582,912 B

    hipLaunchKernelGGL(qk_proj, dim3(64, 24), dim3(256), 0, stream,
                       x, w_in, b_in, qws, kws);
    hipLaunchKernelGGL(v_proj, dim3(64, 12), dim3(256), 0, stream,
                       x, w_in, b_in, vws);
    hipLaunchKernelGGL(scores32, dim3(NN / 128, BB * HH), dim3(256), 0, stream,
                       qws, kws, attn_out);
    hipLaunchKernelGGL(topk_select, dim3(BB * HH * (NN / 4)), dim3(256), 0, stream,
                       qws, kws, vws, attn_out, xatt);
    hipLaunchKernelGGL(out_proj, dim3(64, 12), dim3(256), 0, stream,
                       xatt, w_out, b_out, xout);
}

// Round 6
// 612.285 us; speedup vs baseline: 3.2054x; 1.1427x over previous
//
#include <hip/hip_runtime.h>
#include <math.h>
#include <stdint.h>

#define BB 4
#define NN 1024
#define CC 768
#define HH 12
#define DH 64
#define KTOP 16

typedef __attribute__((ext_vector_type(4))) double f64x4;

// ---------------- Kernel 1a: Q/K projection — fp64 MFMA with layout probe ------------
// out[m][col] = sum_c x[m][c] * w[col][c] + bias[col], col in [0,1536)
// 64x64 block tile, 4 waves (2x2), each wave 32x32 via 2x2 mfma_f64_16x16x4 tiles.
// C/D fragment layout determined AT RUNTIME by two probe MFMAs (layout-agnostic).
__global__ __launch_bounds__(256) void qk_proj(
    const float* __restrict__ x, const float* __restrict__ w,
    const float* __restrict__ bias,
    double* __restrict__ qws, double* __restrict__ kws) {
    __shared__ float x_l[64][33];
    __shared__ float w_l[64][33];
    const int tid = threadIdx.x;
    const int m0 = blockIdx.x * 64, n0 = blockIdx.y * 64;   // n0 in [0,1536)
    const int wave = tid >> 6, lane = tid & 63;
    const int wr = wave >> 1, wc = wave & 1;                // 2x2 wave grid
    const int lr = lane & 15, lk = lane >> 4;               // A/B fragment coords

    // --- runtime C/D layout probe: D1[i][j] = 4*i, D2[i][j] = 4*j ---
    f64x4 pr = {0.0, 0.0, 0.0, 0.0};
    f64x4 pc = {0.0, 0.0, 0.0, 0.0};
    pr = __builtin_amdgcn_mfma_f64_16x16x4f64((double)lr, 1.0, pr, 0, 0, 0);
    pc = __builtin_amdgcn_mfma_f64_16x16x4f64(1.0, (double)lr, pc, 0, 0, 0);
    int rp[4], cp[4];
#pragma unroll
    for (int i = 0; i < 4; ++i) {
        rp[i] = (int)(pr[i] * 0.25 + 0.5);
        cp[i] = (int)(pc[i] * 0.25 + 0.5);
    }

    f64x4 acc[2][2];
#pragma unroll
    for (int i = 0; i < 2; ++i)
#pragma unroll
        for (int j = 0; j < 2; ++j) acc[i][j] = (f64x4)0.0;

    for (int k0 = 0; k0 < CC; k0 += 32) {
        __syncthreads();
#pragma unroll
        for (int h = 0; h < 2; ++h) {
            int e = tid + 256 * h;              // 512 float4 slots: 64 rows x 8
            int row = e >> 3, c4 = (e & 7) << 2;
            float4 xv = *reinterpret_cast<const float4*>(&x[(size_t)(m0 + row) * CC + k0 + c4]);
            float4 wv = *reinterpret_cast<const float4*>(&w[(size_t)(n0 + row) * CC + k0 + c4]);
            x_l[row][c4 + 0] = xv.x; x_l[row][c4 + 1] = xv.y;
            x_l[row][c4 + 2] = xv.z; x_l[row][c4 + 3] = xv.w;
            w_l[row][c4 + 0] = wv.x; w_l[row][c4 + 1] = wv.y;
            w_l[row][c4 + 2] = wv.z; w_l[row][c4 + 3] = wv.w;
        }
        __syncthreads();

#pragma unroll
        for (int kk = 0; kk < 32; kk += 4) {
            int kl = kk + lk;
            double a0 = (double)x_l[wr * 32 + lr][kl];
            double a1 = (double)x_l[wr * 32 + 16 + lr][kl];
            double b0 = (double)w_l[wc * 32 + lr][kl];
            double b1 = (double)w_l[wc * 32 + 16 + lr][kl];
            acc[0][0] = __builtin_amdgcn_mfma_f64_16x16x4f64(a0, b0, acc[0][0], 0, 0, 0);
            acc[0][1] = __builtin_amdgcn_mfma_f64_16x16x4f64(a0, b1, acc[0][1], 0, 0, 0);
            acc[1][0] = __builtin_amdgcn_mfma_f64_16x16x4f64(a1, b0, acc[1][0], 0, 0, 0);
            acc[1][1] = __builtin_amdgcn_mfma_f64_16x16x4f64(a1, b1, acc[1][1], 0, 0, 0);
        }
    }

    // epilogue: scatter through the PROBED C/D layout (rp[i], cp[i])
#pragma unroll
    for (int tr = 0; tr < 2; ++tr) {
#pragma unroll
        for (int tc = 0; tc < 2; ++tc) {
#pragma unroll
            for (int i = 0; i < 4; ++i) {
                int m = m0 + wr * 32 + tr * 16 + rp[i];
                int col = n0 + wc * 32 + tc * 16 + cp[i];
                double val = acc[tr][tc][i] + (double)bias[col];
                int t = (col >= CC);
                int rem = col - (t ? CC : 0);
                int hh = rem >> 6, d = rem & 63;
                int b = m >> 10, n = m & 1023;
                size_t off = (((size_t)(b * HH + hh)) * NN + n) * DH + d;
                if (t == 0) qws[off] = val;
                else kws[off] = val;
            }
        }
    }
}

// ---------------- Kernel 1b: V projection (fp32 — rank-insensitive) ----------------
__global__ __launch_bounds__(256) void v_proj(
    const float* __restrict__ x, const float* __restrict__ w,
    const float* __restrict__ bias, float* __restrict__ vws) {
    __shared__ float a_lds[64][17];
    __shared__ float b_lds[64][17];
    const int tid = threadIdx.x;
    const int m0 = blockIdx.x * 64, n0 = blockIdx.y * 64;   // n0 in [0,768)
    const int ty = tid >> 4, tx = tid & 15;
    const int lr = tid >> 2, lc = (tid & 3) << 2;

    float acc[4][4];
#pragma unroll
    for (int i = 0; i < 4; ++i)
#pragma unroll
        for (int j = 0; j < 4; ++j) acc[i][j] = 0.0f;

    for (int k0 = 0; k0 < CC; k0 += 16) {
        float4 av = *reinterpret_cast<const float4*>(&x[(size_t)(m0 + lr) * CC + k0 + lc]);
        float4 wv = *reinterpret_cast<const float4*>(&w[(size_t)(1536 + n0 + lr) * CC + k0 + lc]);
        __syncthreads();
        a_lds[lr][lc + 0] = av.x; a_lds[lr][lc + 1] = av.y;
        a_lds[lr][lc + 2] = av.z; a_lds[lr][lc + 3] = av.w;
        b_lds[lr][lc + 0] = wv.x; b_lds[lr][lc + 1] = wv.y;
        b_lds[lr][lc + 2] = wv.z; b_lds[lr][lc + 3] = wv.w;
        __syncthreads();
#pragma unroll
        for (int kk = 0; kk < 16; ++kk) {
            float a0 = a_lds[ty + 0][kk];
            float a1 = a_lds[ty + 16][kk];
            float a2 = a_lds[ty + 32][kk];
            float a3 = a_lds[ty + 48][kk];
            float w0 = b_lds[tx + 0][kk];
            float w1 = b_lds[tx + 16][kk];
            float w2 = b_lds[tx + 32][kk];
            float w3 = b_lds[tx + 48][kk];
            acc[0][0] = fmaf(a0, w0, acc[0][0]); acc[0][1] = fmaf(a0, w1, acc[0][1]);
            acc[0][2] = fmaf(a0, w2, acc[0][2]); acc[0][3] = fmaf(a0, w3, acc[0][3]);
            acc[1][0] = fmaf(a1, w0, acc[1][0]); acc[1][1] = fmaf(a1, w1, acc[1][1]);
            acc[1][2] = fmaf(a1, w2, acc[1][2]); acc[1][3] = fmaf(a1, w3, acc[1][3]);
            acc[2][0] = fmaf(a2, w0, acc[2][0]); acc[2][1] = fmaf(a2, w1, acc[2][1]);
            acc[2][2] = fmaf(a2, w2, acc[2][2]); acc[2][3] = fmaf(a2, w3, acc[2][3]);
            acc[3][0] = fmaf(a3, w0, acc[3][0]); acc[3][1] = fmaf(a3, w1, acc[3][1]);
            acc[3][2] = fmaf(a3, w2, acc[3][2]); acc[3][3] = fmaf(a3, w3, acc[3][3]);
        }
    }

#pragma unroll
    for (int i = 0; i < 4; ++i) {
#pragma unroll
        for (int j = 0; j < 4; ++j) {
            int m = m0 + ty + i * 16;
            int col = n0 + tx + j * 16;              // [0,768)
            float val = acc[i][j] + bias[1536 + col];
            int h = col >> 6, d = col & 63;
            int b = m >> 10, n = m & 1023;
            vws[(((size_t)(b * HH + h)) * NN + n) * DH + d] = val;
        }
    }
}

// ---------------- Kernel 2a: fp32 scores GEMM -> raw scores into attn region ----------------
__global__ __launch_bounds__(256) void scores32(
    const double* __restrict__ q64, const double* __restrict__ k64,
    float* __restrict__ attn_out) {
    __shared__ float qs[128][64];
    __shared__ float ks[128][64];
    const int bh = blockIdx.y;
    const int m0 = blockIdx.x * 128;
    const int tid = threadIdx.x;
    const int ty = tid >> 4, tx = tid & 15;

    const double* qb = q64 + ((size_t)bh * NN + m0) * DH;
    const double* kb = k64 + (size_t)bh * NN * DH;

#pragma unroll
    for (int wv = 0; wv < 8; ++wv) {
        int e = tid + 256 * wv;
        int row = e >> 4, d4 = e & 15;
        const double* src = qb + (size_t)row * DH + d4 * 4;
        float4 f;
        f.x = (float)(src[0] * 0.125); f.y = (float)(src[1] * 0.125);
        f.z = (float)(src[2] * 0.125); f.w = (float)(src[3] * 0.125);
        ((float4*)qs[row])[d4 ^ ((row >> 3) & 15)] = f;
    }

    float* orow0 = attn_out + ((size_t)bh * NN + m0) * NN;

    for (int c0 = 0; c0 < NN; c0 += 128) {
        __syncthreads();
#pragma unroll
        for (int wv = 0; wv < 8; ++wv) {
            int e = tid + 256 * wv;
            int col = e >> 4, d4 = e & 15;
            const double* src = kb + (size_t)(c0 + col) * DH + d4 * 4;
            float4 f;
            f.x = (float)src[0]; f.y = (float)src[1];
            f.z = (float)src[2]; f.w = (float)src[3];
            ((float4*)ks[col])[d4 ^ ((col >> 3) & 15)] = f;
        }
        __syncthreads();

        float acc[8][8];
#pragma unroll
        for (int i = 0; i < 8; ++i)
#pragma unroll
            for (int j = 0; j < 8; ++j) acc[i][j] = 0.0f;

#pragma unroll
        for (int d4 = 0; d4 < 16; ++d4) {
            float4 a4[8];
#pragma unroll
            for (int i = 0; i < 8; ++i)
                a4[i] = ((float4*)qs[8 * ty + i])[d4 ^ ty];
#pragma unroll
            for (int j = 0; j < 8; ++j) {
                float4 b4 = ((float4*)ks[8 * tx + j])[d4 ^ tx];
#pragma unroll
                for (int i = 0; i < 8; ++i) {
                    acc[i][j] = fmaf(a4[i].x, b4.x, acc[i][j]);
                    acc[i][j] = fmaf(a4[i].y, b4.y, acc[i][j]);
                    acc[i][j] = fmaf(a4[i].z, b4.z, acc[i][j]);
                    acc[i][j] = fmaf(a4[i].w, b4.w, acc[i][j]);
                }
            }
        }

#pragma unroll
        for (int i = 0; i < 8; ++i) {
#pragma unroll
            for (int jj = 0; jj < 2; ++jj) {
                float4 o;
                o.x = acc[i][4 * jj + 0]; o.y = acc[i][4 * jj + 1];
                o.z = acc[i][4 * jj + 2]; o.w = acc[i][4 * jj + 3];
                *(float4*)&orow0[(size_t)(8 * ty + i) * NN + c0 + 8 * tx + 4 * jj] = o;
            }
        }
    }
}

// ---------------- Kernel 2b: bitonic top-16 with margin-gated fp64 fallback ----------------
__device__ __forceinline__ uint32_t f2su(float f) {
    uint32_t u = __float_as_uint(f);
    return u ^ ((u & 0x80000000u) ? 0xFFFFFFFFu : 0x80000000u);
}
__device__ __forceinline__ float su2f(uint32_t s) {
    uint32_t u = s ^ ((s & 0x80000000u) ? 0x80000000u : 0xFFFFFFFFu);
    return __uint_as_float(u);
}

__global__ __launch_bounds__(256) void topk_select(
    const double* __restrict__ q64, const double* __restrict__ k64,
    const float* __restrict__ v32,
    float* __restrict__ attn_out, float* __restrict__ xatt) {
    __shared__ int      cand_idx[4][64];
    __shared__ uint32_t cand_val[4][64];
    const int blk = blockIdx.x;
    const int wave = threadIdx.x >> 6, lane = threadIdx.x & 63;
    const int bh = blk >> 8;
    const int qn = ((blk & 255) << 2) | wave;

    float* srow = attn_out + ((size_t)bh * NN + qn) * NN;

    // load 16 scores, transform to order-preserving sortable uint
    uint32_t su[16];
#pragma unroll
    for (int i = 0; i < 4; ++i) {
        float4 t = *(const float4*)&srow[i * 256 + lane * 4];
        su[4 * i + 0] = f2su(t.x); su[4 * i + 1] = f2su(t.y);
        su[4 * i + 2] = f2su(t.z); su[4 * i + 3] = f2su(t.w);
    }

    // binary search MSB->LSB: largest thr with count(su >= thr) >= 17; early-exit in [17,64]
    uint32_t thr = 0;
    for (int b = 31; b >= 0; --b) {
        uint32_t test = thr | (1u << b);
        int cnt = 0;
#pragma unroll
        for (int r = 0; r < 16; ++r)
            cnt += __popcll(__ballot(su[r] >= test));
        if (cnt >= 17) { thr = test; if (cnt <= 64) break; }
    }

    // compact (value, column) candidates into LDS (column order)
    int C = 0;
#pragma unroll
    for (int r = 0; r < 16; ++r) {
        bool pr = (su[r] >= thr);
        unsigned long long mask = __ballot(pr);
        if (pr) {
            int pos = C + __popcll(mask & ((1ull << lane) - 1ull));
            if (pos < 64) {
                cand_idx[wave][pos] = ((r >> 2) << 8) + (lane << 2) + (r & 3);
                cand_val[wave][pos] = su[r];
            }
        }
        C += __popcll(mask);
    }
    if (C > 64) C = 64;

    uint32_t key = (lane < C) ? cand_val[wave][lane] : 0u;
    int      idx = (lane < C) ? cand_idx[wave][lane] : (0x40000000 + lane);

    // bitonic sort 64 lanes: (key desc, idx asc)  — 21 exchange steps
#pragma unroll
    for (int k = 2; k <= 64; k <<= 1) {
#pragma unroll
        for (int j = k >> 1; j > 0; j >>= 1) {
            uint32_t ok = __shfl_xor(key, j);
            int      oi = __shfl_xor(idx, j);
            bool mine_better = (key > ok) || (key == ok && idx < oi);
            bool lower = ((lane & j) == 0);
            bool dir_desc = ((lane & k) == 0);
            bool keep = dir_desc ? (lower ? mine_better : !mine_better)
                                 : (lower ? !mine_better : mine_better);
            if (!keep) { key = ok; idx = oi; }
        }
    }

    float f = su2f(key);                  // valid for lane < C (C >= 17)
    float f15 = __shfl(f, 15);
    float f16 = __shfl(f, 16);

    float p = 0.0f;
    int selIdx = idx;

    if (f15 - f16 > 2e-4f) {
        // ---- fast path: fp32 ordering provably matches fp64 at the 16/17 boundary ----
        float m = __shfl(f, 0);
        float e = (lane < KTOP) ? expf(f - m) : 0.0f;
        float sum = e;
#pragma unroll
        for (int off = 32; off; off >>= 1) sum += __shfl_xor(sum, off);
        p = e / sum;
    } else {
        // ---- slow path (~0.8% of rows): fp64 rescore of all candidates near boundary ----
        uint32_t thr2 = f2su(f15 - 4e-4f);
        int C2 = 0;
#pragma unroll
        for (int r = 0; r < 16; ++r) {
            bool pr = (su[r] >= thr2);
            unsigned long long mask = __ballot(pr);
            if (pr) {
                int pos = C2 + __popcll(mask & ((1ull << lane) - 1ull));
                if (pos < 64) cand_idx[wave][pos] = ((r >> 2) << 8) + (lane << 2) + (r & 3);
            }
            C2 += __popcll(mask);
        }
        if (C2 > 64) C2 = 64;
        int cand = cand_idx[wave][lane < C2 ? lane : 0];

        const double qd = q64[((size_t)bh * NN + qn) * DH + lane];
        const double* kb = k64 + (size_t)bh * NN * DH;
        double myS = -1.0e300;
        int myI = (1 << 30);
#pragma unroll 1
        for (int t = 0; t < C2; ++t) {
            int jt = __shfl(cand, t);
            double pr = qd * kb[(size_t)jt * DH + lane];
#pragma unroll
            for (int off = 32; off; off >>= 1) pr += __shfl_xor(pr, off);
            if (lane == t) { myS = pr * 0.125; myI = jt; }
        }

        // exact fp64 top-16 among C2 (tie -> lower index); rank t lands on lane t
        double sS = myS;
        int sI = myI;
        double selS = 0.0;
#pragma unroll 1
        for (int t = 0; t < KTOP; ++t) {
            double bv = sS; int bi = sI;
#pragma unroll
            for (int off = 32; off; off >>= 1) {
                double ov = __shfl_xor(bv, off);
                int oi = __shfl_xor(bi, off);
                if (ov > bv || (ov == bv && oi < bi)) { bv = ov; bi = oi; }
            }
            if (lane == t) { selS = bv; selIdx = bi; }
            if (sI == bi) sS = -1.0e300;
        }

        double m = __shfl(selS, 0);
        float e = (lane < KTOP) ? expf((float)(selS - m)) : 0.0f;
        float sum = e;
#pragma unroll
        for (int off = 32; off; off >>= 1) sum += __shfl_xor(sum, off);
        p = e / sum;
    }

    // ---- shared tail: AV, zero-fill row, scatter probs, write xatt ----
    const float* vb = v32 + (size_t)bh * NN * DH;
    float o = 0.0f;
#pragma unroll
    for (int t = 0; t < KTOP; ++t) {
        int jt = __shfl(selIdx, t);
        float pt = __shfl(p, t);
        o = fmaf(pt, vb[(size_t)jt * DH + lane], o);
    }

#pragma unroll
    for (int i = 0; i < 4; ++i) {
        float4 z = make_float4(0.f, 0.f, 0.f, 0.f);
        *(float4*)&srow[i * 256 + lane * 4] = z;
    }
    asm volatile("s_waitcnt vmcnt(0)" ::: "memory");
    if (lane < KTOP) srow[selIdx] = p;

    int b = bh / HH, h = bh - b * HH;
    xatt[((size_t)b * NN + qn) * CC + h * DH + lane] = o;
}

// ---------------- Kernel 3: output projection (fp32) ----------------
__global__ __launch_bounds__(256) void out_proj(
    const float* __restrict__ a, const float* __restrict__ w,
    const float* __restrict__ bias, float* __restrict__ out) {
    __shared__ float a_lds[64][17];
    __shared__ float b_lds[64][17];
    const int tid = threadIdx.x;
    const int m0 = blockIdx.x * 64, n0 = blockIdx.y * 64;
    const int ty = tid >> 4, tx = tid & 15;
    const int lr = tid >> 2, lc = (tid & 3) << 2;

    float acc[4][4];
#pragma unroll
    for (int i = 0; i < 4; ++i)
#pragma unroll
        for (int j = 0; j < 4; ++j) acc[i][j] = 0.0f;

    for (int k0 = 0; k0 < CC; k0 += 16) {
        float4 av = *reinterpret_cast<const float4*>(&a[(size_t)(m0 + lr) * CC + k0 + lc]);
        float4 wv = *reinterpret_cast<const float4*>(&w[(size_t)(n0 + lr) * CC + k0 + lc]);
        __syncthreads();
        a_lds[lr][lc + 0] = av.x; a_lds[lr][lc + 1] = av.y;
        a_lds[lr][lc + 2] = av.z; a_lds[lr][lc + 3] = av.w;
        b_lds[lr][lc + 0] = wv.x; b_lds[lr][lc + 1] = wv.y;
        b_lds[lr][lc + 2] = wv.z; b_lds[lr][lc + 3] = wv.w;
        __syncthreads();
#pragma unroll
        for (int kk = 0; kk < 16; ++kk) {
            float a0 = a_lds[ty + 0][kk];
            float a1 = a_lds[ty + 16][kk];
            float a2 = a_lds[ty + 32][kk];
            float a3 = a_lds[ty + 48][kk];
            float w0 = b_lds[tx + 0][kk];
            float w1 = b_lds[tx + 16][kk];
            float w2 = b_lds[tx + 32][kk];
            float w3 = b_lds[tx + 48][kk];
            acc[0][0] = fmaf(a0, w0, acc[0][0]); acc[0][1] = fmaf(a0, w1, acc[0][1]);
            acc[0][2] = fmaf(a0, w2, acc[0][2]); acc[0][3] = fmaf(a0, w3, acc[0][3]);
            acc[1][0] = fmaf(a1, w0, acc[1][0]); acc[1][1] = fmaf(a1, w1, acc[1][1]);
            acc[1][2] = fmaf(a1, w2, acc[1][2]); acc[1][3] = fmaf(a1, w3, acc[1][3]);
            acc[2][0] = fmaf(a2, w0, acc[2][0]); acc[2][1] = fmaf(a2, w1, acc[2][1]);
            acc[2][2] = fmaf(a2, w2, acc[2][2]); acc[2][3] = fmaf(a2, w3, acc[2][3]);
            acc[3][0] = fmaf(a3, w0, acc[3][0]); acc[3][1] = fmaf(a3, w1, acc[3][1]);
            acc[3][2] = fmaf(a3, w2, acc[3][2]); acc[3][3] = fmaf(a3, w3, acc[3][3]);
        }
    }

#pragma unroll
    for (int i = 0; i < 4; ++i) {
#pragma unroll
        for (int j = 0; j < 4; ++j) {
            int m = m0 + ty + i * 16;
            int n = n0 + tx + j * 16;
            out[(size_t)m * CC + n] = acc[i][j] + bias[n];
        }
    }
}

extern "C" void kernel_launch(void* const* d_in, const int* in_sizes, int n_in,
                              void* d_out, int out_size, void* d_ws, size_t ws_size,
                              hipStream_t stream) {
    const float* x     = (const float*)d_in[0];
    const float* w_in  = (const float*)d_in[1];
    const float* b_in  = (const float*)d_in[2];
    const float* w_out = (const float*)d_in[3];
    const float* b_out = (const float*)d_in[4];

    float* xout     = (float*)d_out;                        // [B][N][C]
    float* attn_out = (float*)d_out + (size_t)BB * NN * CC; // [B][H][N][N]

    char* ws = (char*)d_ws;
    double* qws  = (double*)ws;                                   // 25,165,824 B
    double* kws  = (double*)(ws + 25165824);                      // 25,165,824 B
    float*  vws  = (float*)(ws + 50331648);                       // 12,582,912 B
    float*  xatt = (float*)(ws + 62914560);                       // 12,582,912 B

    hipLaunchKernelGGL(qk_proj, dim3(64, 24), dim3(256), 0, stream,
                       x, w_in, b_in, qws, kws);
    hipLaunchKernelGGL(v_proj, dim3(64, 12), dim3(256), 0, stream,
                       x, w_in, b_in, vws);
    hipLaunchKernelGGL(scores32, dim3(NN / 128, BB * HH), dim3(256), 0, stream,
                       qws, kws, attn_out);
    hipLaunchKernelGGL(topk_select, dim3(BB * HH * (NN / 4)), dim3(256), 0, stream,
                       qws, kws, vws, attn_out, xatt);
    hipLaunchKernelGGL(out_proj, dim3(64, 12), dim3(256), 0, stream,
                       xatt, w_out, b_out, xout);
}

// Round 7
// 571.857 us; speedup vs baseline: 3.4321x; 1.0707x over previous
//
#include <hip/hip_runtime.h>
#include <math.h>
#include <stdint.h>

#define BB 4
#define NN 1024
#define CC 768
#define HH 12
#define DH 64
#define KTOP 16

typedef __attribute__((ext_vector_type(4))) double f64x4;

// ---------------- Kernel 1a: Q/K projection — fp64 MFMA with layout probe ------------
__global__ __launch_bounds__(256) void qk_proj(
    const float* __restrict__ x, const float* __restrict__ w,
    const float* __restrict__ bias,
    double* __restrict__ qws, double* __restrict__ kws) {
    __shared__ float x_l[64][33];
    __shared__ float w_l[64][33];
    const int tid = threadIdx.x;
    const int m0 = blockIdx.x * 64, n0 = blockIdx.y * 64;   // n0 in [0,1536)
    const int wave = tid >> 6, lane = tid & 63;
    const int wr = wave >> 1, wc = wave & 1;                // 2x2 wave grid
    const int lr = lane & 15, lk = lane >> 4;               // A/B fragment coords

    // --- runtime C/D layout probe: D1[i][j] = 4*i, D2[i][j] = 4*j ---
    f64x4 pr = {0.0, 0.0, 0.0, 0.0};
    f64x4 pc = {0.0, 0.0, 0.0, 0.0};
    pr = __builtin_amdgcn_mfma_f64_16x16x4f64((double)lr, 1.0, pr, 0, 0, 0);
    pc = __builtin_amdgcn_mfma_f64_16x16x4f64(1.0, (double)lr, pc, 0, 0, 0);
    int rp[4], cp[4];
#pragma unroll
    for (int i = 0; i < 4; ++i) {
        rp[i] = (int)(pr[i] * 0.25 + 0.5);
        cp[i] = (int)(pc[i] * 0.25 + 0.5);
    }

    f64x4 acc[2][2];
#pragma unroll
    for (int i = 0; i < 2; ++i)
#pragma unroll
        for (int j = 0; j < 2; ++j) acc[i][j] = (f64x4)0.0;

    for (int k0 = 0; k0 < CC; k0 += 32) {
        __syncthreads();
#pragma unroll
        for (int h = 0; h < 2; ++h) {
            int e = tid + 256 * h;              // 512 float4 slots: 64 rows x 8
            int row = e >> 3, c4 = (e & 7) << 2;
            float4 xv = *reinterpret_cast<const float4*>(&x[(size_t)(m0 + row) * CC + k0 + c4]);
            float4 wv = *reinterpret_cast<const float4*>(&w[(size_t)(n0 + row) * CC + k0 + c4]);
            x_l[row][c4 + 0] = xv.x; x_l[row][c4 + 1] = xv.y;
            x_l[row][c4 + 2] = xv.z; x_l[row][c4 + 3] = xv.w;
            w_l[row][c4 + 0] = wv.x; w_l[row][c4 + 1] = wv.y;
            w_l[row][c4 + 2] = wv.z; w_l[row][c4 + 3] = wv.w;
        }
        __syncthreads();

#pragma unroll
        for (int kk = 0; kk < 32; kk += 4) {
            int kl = kk + lk;
            double a0 = (double)x_l[wr * 32 + lr][kl];
            double a1 = (double)x_l[wr * 32 + 16 + lr][kl];
            double b0 = (double)w_l[wc * 32 + lr][kl];
            double b1 = (double)w_l[wc * 32 + 16 + lr][kl];
            acc[0][0] = __builtin_amdgcn_mfma_f64_16x16x4f64(a0, b0, acc[0][0], 0, 0, 0);
            acc[0][1] = __builtin_amdgcn_mfma_f64_16x16x4f64(a0, b1, acc[0][1], 0, 0, 0);
            acc[1][0] = __builtin_amdgcn_mfma_f64_16x16x4f64(a1, b0, acc[1][0], 0, 0, 0);
            acc[1][1] = __builtin_amdgcn_mfma_f64_16x16x4f64(a1, b1, acc[1][1], 0, 0, 0);
        }
    }

    // epilogue: scatter through the PROBED C/D layout (rp[i], cp[i])
#pragma unroll
    for (int tr = 0; tr < 2; ++tr) {
#pragma unroll
        for (int tc = 0; tc < 2; ++tc) {
#pragma unroll
            for (int i = 0; i < 4; ++i) {
                int m = m0 + wr * 32 + tr * 16 + rp[i];
                int col = n0 + wc * 32 + tc * 16 + cp[i];
                double val = acc[tr][tc][i] + (double)bias[col];
                int t = (col >= CC);
                int rem = col - (t ? CC : 0);
                int hh = rem >> 6, d = rem & 63;
                int b = m >> 10, n = m & 1023;
                size_t off = (((size_t)(b * HH + hh)) * NN + n) * DH + d;
                if (t == 0) qws[off] = val;
                else kws[off] = val;
            }
        }
    }
}

// ---------------- Kernel 1b: V projection (fp32 — rank-insensitive) ----------------
__global__ __launch_bounds__(256) void v_proj(
    const float* __restrict__ x, const float* __restrict__ w,
    const float* __restrict__ bias, float* __restrict__ vws) {
    __shared__ float a_lds[64][17];
    __shared__ float b_lds[64][17];
    const int tid = threadIdx.x;
    const int m0 = blockIdx.x * 64, n0 = blockIdx.y * 64;   // n0 in [0,768)
    const int ty = tid >> 4, tx = tid & 15;
    const int lr = tid >> 2, lc = (tid & 3) << 2;

    float acc[4][4];
#pragma unroll
    for (int i = 0; i < 4; ++i)
#pragma unroll
        for (int j = 0; j < 4; ++j) acc[i][j] = 0.0f;

    for (int k0 = 0; k0 < CC; k0 += 16) {
        float4 av = *reinterpret_cast<const float4*>(&x[(size_t)(m0 + lr) * CC + k0 + lc]);
        float4 wv = *reinterpret_cast<const float4*>(&w[(size_t)(1536 + n0 + lr) * CC + k0 + lc]);
        __syncthreads();
        a_lds[lr][lc + 0] = av.x; a_lds[lr][lc + 1] = av.y;
        a_lds[lr][lc + 2] = av.z; a_lds[lr][lc + 3] = av.w;
        b_lds[lr][lc + 0] = wv.x; b_lds[lr][lc + 1] = wv.y;
        b_lds[lr][lc + 2] = wv.z; b_lds[lr][lc + 3] = wv.w;
        __syncthreads();
#pragma unroll
        for (int kk = 0; kk < 16; ++kk) {
            float a0 = a_lds[ty + 0][kk];
            float a1 = a_lds[ty + 16][kk];
            float a2 = a_lds[ty + 32][kk];
            float a3 = a_lds[ty + 48][kk];
            float w0 = b_lds[tx + 0][kk];
            float w1 = b_lds[tx + 16][kk];
            float w2 = b_lds[tx + 32][kk];
            float w3 = b_lds[tx + 48][kk];
            acc[0][0] = fmaf(a0, w0, acc[0][0]); acc[0][1] = fmaf(a0, w1, acc[0][1]);
            acc[0][2] = fmaf(a0, w2, acc[0][2]); acc[0][3] = fmaf(a0, w3, acc[0][3]);
            acc[1][0] = fmaf(a1, w0, acc[1][0]); acc[1][1] = fmaf(a1, w1, acc[1][1]);
            acc[1][2] = fmaf(a1, w2, acc[1][2]); acc[1][3] = fmaf(a1, w3, acc[1][3]);
            acc[2][0] = fmaf(a2, w0, acc[2][0]); acc[2][1] = fmaf(a2, w1, acc[2][1]);
            acc[2][2] = fmaf(a2, w2, acc[2][2]); acc[2][3] = fmaf(a2, w3, acc[2][3]);
            acc[3][0] = fmaf(a3, w0, acc[3][0]); acc[3][1] = fmaf(a3, w1, acc[3][1]);
            acc[3][2] = fmaf(a3, w2, acc[3][2]); acc[3][3] = fmaf(a3, w3, acc[3][3]);
        }
    }

#pragma unroll
    for (int i = 0; i < 4; ++i) {
#pragma unroll
        for (int j = 0; j < 4; ++j) {
            int m = m0 + ty + i * 16;
            int col = n0 + tx + j * 16;              // [0,768)
            float val = acc[i][j] + bias[1536 + col];
            int h = col >> 6, d = col & 63;
            int b = m >> 10, n = m & 1023;
            vws[(((size_t)(b * HH + h)) * NN + n) * DH + d] = val;
        }
    }
}

// ---------------- Kernel 2a: fp32 scores GEMM (64-row blocks, 3 blocks/CU) ----------------
__global__ __launch_bounds__(256) void scores32(
    const double* __restrict__ q64, const double* __restrict__ k64,
    float* __restrict__ attn_out) {
    __shared__ float qs[64][64];    // 16KB, swizzled float4 slots
    __shared__ float ks[128][64];   // 32KB
    const int bh = blockIdx.y;
    const int m0 = blockIdx.x * 64;
    const int tid = threadIdx.x;
    const int ty = tid >> 4, tx = tid & 15;

    const double* qb = q64 + ((size_t)bh * NN + m0) * DH;
    const double* kb = k64 + (size_t)bh * NN * DH;

    // stage q tile once (fp64->fp32, fold 0.125, swizzle): 1024 float4 slots
#pragma unroll
    for (int wv = 0; wv < 4; ++wv) {
        int e = tid + 256 * wv;             // 0..1023
        int row = e >> 4, d4 = e & 15;
        const double* src = qb + (size_t)row * DH + d4 * 4;
        float4 f;
        f.x = (float)(src[0] * 0.125); f.y = (float)(src[1] * 0.125);
        f.z = (float)(src[2] * 0.125); f.w = (float)(src[3] * 0.125);
        ((float4*)qs[row])[d4 ^ (row >> 3)] = f;     // row>>3 in 0..7
    }

    float* orow0 = attn_out + ((size_t)bh * NN + m0) * NN;

    for (int c0 = 0; c0 < NN; c0 += 128) {
        __syncthreads();
#pragma unroll
        for (int wv = 0; wv < 8; ++wv) {
            int e = tid + 256 * wv;         // 0..2047
            int col = e >> 4, d4 = e & 15;
            const double* src = kb + (size_t)(c0 + col) * DH + d4 * 4;
            float4 f;
            f.x = (float)src[0]; f.y = (float)src[1];
            f.z = (float)src[2]; f.w = (float)src[3];
            ((float4*)ks[col])[d4 ^ ((col >> 3) & 15)] = f;
        }
        __syncthreads();

        float acc[4][8];
#pragma unroll
        for (int i = 0; i < 4; ++i)
#pragma unroll
            for (int j = 0; j < 8; ++j) acc[i][j] = 0.0f;

#pragma unroll
        for (int d4 = 0; d4 < 16; ++d4) {
            float4 a4[4];
#pragma unroll
            for (int i = 0; i < 4; ++i)
                a4[i] = ((float4*)qs[4 * ty + i])[d4 ^ ((4 * ty + i) >> 3)];
#pragma unroll
            for (int j = 0; j < 8; ++j) {
                float4 b4 = ((float4*)ks[8 * tx + j])[d4 ^ tx];
#pragma unroll
                for (int i = 0; i < 4; ++i) {
                    acc[i][j] = fmaf(a4[i].x, b4.x, acc[i][j]);
                    acc[i][j] = fmaf(a4[i].y, b4.y, acc[i][j]);
                    acc[i][j] = fmaf(a4[i].z, b4.z, acc[i][j]);
                    acc[i][j] = fmaf(a4[i].w, b4.w, acc[i][j]);
                }
            }
        }

        // store raw scores (scale folded into q)
#pragma unroll
        for (int i = 0; i < 4; ++i) {
#pragma unroll
            for (int jj = 0; jj < 2; ++jj) {
                float4 o;
                o.x = acc[i][4 * jj + 0]; o.y = acc[i][4 * jj + 1];
                o.z = acc[i][4 * jj + 2]; o.w = acc[i][4 * jj + 3];
                *(float4*)&orow0[(size_t)(4 * ty + i) * NN + c0 + 8 * tx + 4 * jj] = o;
            }
        }
    }
}

// ---------------- Kernel 2b: bitonic top-16 with margin-gated fp64 fallback ----------------
__device__ __forceinline__ uint32_t f2su(float f) {
    uint32_t u = __float_as_uint(f);
    return u ^ ((u & 0x80000000u) ? 0xFFFFFFFFu : 0x80000000u);
}
__device__ __forceinline__ float su2f(uint32_t s) {
    uint32_t u = s ^ ((s & 0x80000000u) ? 0x80000000u : 0xFFFFFFFFu);
    return __uint_as_float(u);
}

__global__ __launch_bounds__(256) void topk_select(
    const double* __restrict__ q64, const double* __restrict__ k64,
    const float* __restrict__ v32,
    float* __restrict__ attn_out, float* __restrict__ xatt) {
    __shared__ int      cand_idx[4][64];
    __shared__ uint32_t cand_val[4][64];
    const int blk = blockIdx.x;
    const int wave = threadIdx.x >> 6, lane = threadIdx.x & 63;
    const int bh = blk >> 8;
    const int qn = ((blk & 255) << 2) | wave;

    float* srow = attn_out + ((size_t)bh * NN + qn) * NN;

    // load 16 scores, transform to order-preserving sortable uint
    uint32_t su[16];
#pragma unroll
    for (int i = 0; i < 4; ++i) {
        float4 t = *(const float4*)&srow[i * 256 + lane * 4];
        su[4 * i + 0] = f2su(t.x); su[4 * i + 1] = f2su(t.y);
        su[4 * i + 2] = f2su(t.z); su[4 * i + 3] = f2su(t.w);
    }

    // binary search MSB->LSB: largest thr with count(su >= thr) >= 17; early-exit in [17,64]
    uint32_t thr = 0;
    for (int b = 31; b >= 0; --b) {
        uint32_t test = thr | (1u << b);
        int cnt = 0;
#pragma unroll
        for (int r = 0; r < 16; ++r)
            cnt += __popcll(__ballot(su[r] >= test));
        if (cnt >= 17) { thr = test; if (cnt <= 64) break; }
    }

    // compact (value, column) candidates into LDS (column order)
    int C = 0;
#pragma unroll
    for (int r = 0; r < 16; ++r) {
        bool pr = (su[r] >= thr);
        unsigned long long mask = __ballot(pr);
        if (pr) {
            int pos = C + __popcll(mask & ((1ull << lane) - 1ull));
            if (pos < 64) {
                cand_idx[wave][pos] = ((r >> 2) << 8) + (lane << 2) + (r & 3);
                cand_val[wave][pos] = su[r];
            }
        }
        C += __popcll(mask);
    }
    if (C > 64) C = 64;

    uint32_t key = (lane < C) ? cand_val[wave][lane] : 0u;
    int      idx = (lane < C) ? cand_idx[wave][lane] : (0x40000000 + lane);

    // bitonic sort 64 lanes: (key desc, idx asc)  — 21 exchange steps
#pragma unroll
    for (int k = 2; k <= 64; k <<= 1) {
#pragma unroll
        for (int j = k >> 1; j > 0; j >>= 1) {
            uint32_t ok = __shfl_xor(key, j);
            int      oi = __shfl_xor(idx, j);
            bool mine_better = (key > ok) || (key == ok && idx < oi);
            bool lower = ((lane & j) == 0);
            bool dir_desc = ((lane & k) == 0);
            bool keep = dir_desc ? (lower ? mine_better : !mine_better)
                                 : (lower ? !mine_better : mine_better);
            if (!keep) { key = ok; idx = oi; }
        }
    }

    float f = su2f(key);                  // valid for lane < C (C >= 17)
    float f15 = __shfl(f, 15);
    float f16 = __shfl(f, 16);

    float p = 0.0f;
    int selIdx = idx;

    if (f15 - f16 > 2e-4f) {
        // ---- fast path: fp32 ordering provably matches fp64 at the 16/17 boundary ----
        float m = __shfl(f, 0);
        float e = (lane < KTOP) ? expf(f - m) : 0.0f;
        float sum = e;
#pragma unroll
        for (int off = 32; off; off >>= 1) sum += __shfl_xor(sum, off);
        p = e / sum;
    } else {
        // ---- slow path (~1% of rows): fp64 rescore of all candidates near boundary ----
        uint32_t thr2 = f2su(f15 - 4e-4f);
        int C2 = 0;
#pragma unroll
        for (int r = 0; r < 16; ++r) {
            bool pr = (su[r] >= thr2);
            unsigned long long mask = __ballot(pr);
            if (pr) {
                int pos = C2 + __popcll(mask & ((1ull << lane) - 1ull));
                if (pos < 64) cand_idx[wave][pos] = ((r >> 2) << 8) + (lane << 2) + (r & 3);
            }
            C2 += __popcll(mask);
        }
        if (C2 > 64) C2 = 64;
        int cand = cand_idx[wave][lane < C2 ? lane : 0];

        const double qd = q64[((size_t)bh * NN + qn) * DH + lane];
        const double* kb = k64 + (size_t)bh * NN * DH;
        double myS = -1.0e300;
        int myI = (1 << 30);
#pragma unroll 1
        for (int t = 0; t < C2; ++t) {
            int jt = __shfl(cand, t);
            double pr = qd * kb[(size_t)jt * DH + lane];
#pragma unroll
            for (int off = 32; off; off >>= 1) pr += __shfl_xor(pr, off);
            if (lane == t) { myS = pr * 0.125; myI = jt; }
        }

        // exact fp64 top-16 among C2 (tie -> lower index); rank t lands on lane t
        double sS = myS;
        int sI = myI;
        double selS = 0.0;
#pragma unroll 1
        for (int t = 0; t < KTOP; ++t) {
            double bv = sS; int bi = sI;
#pragma unroll
            for (int off = 32; off; off >>= 1) {
                double ov = __shfl_xor(bv, off);
                int oi = __shfl_xor(bi, off);
                if (ov > bv || (ov == bv && oi < bi)) { bv = ov; bi = oi; }
            }
            if (lane == t) { selS = bv; selIdx = bi; }
            if (sI == bi) sS = -1.0e300;
        }

        double m = __shfl(selS, 0);
        float e = (lane < KTOP) ? expf((float)(selS - m)) : 0.0f;
        float sum = e;
#pragma unroll
        for (int off = 32; off; off >>= 1) sum += __shfl_xor(sum, off);
        p = e / sum;
    }

    // ---- shared tail: AV, zero-fill row, scatter probs, write xatt ----
    const float* vb = v32 + (size_t)bh * NN * DH;
    float o = 0.0f;
#pragma unroll
    for (int t = 0; t < KTOP; ++t) {
        int jt = __shfl(selIdx, t);
        float pt = __shfl(p, t);
        o = fmaf(pt, vb[(size_t)jt * DH + lane], o);
    }

#pragma unroll
    for (int i = 0; i < 4; ++i) {
        float4 z = make_float4(0.f, 0.f, 0.f, 0.f);
        *(float4*)&srow[i * 256 + lane * 4] = z;
    }
    asm volatile("s_waitcnt vmcnt(0)" ::: "memory");
    if (lane < KTOP) srow[selIdx] = p;

    int b = bh / HH, h = bh - b * HH;
    xatt[((size_t)b * NN + qn) * CC + h * DH + lane] = o;
}

// ---------------- Kernel 3: output projection (fp32) ----------------
__global__ __launch_bounds__(256) void out_proj(
    const float* __restrict__ a, const float* __restrict__ w,
    const float* __restrict__ bias, float* __restrict__ out) {
    __shared__ float a_lds[64][17];
    __shared__ float b_lds[64][17];
    const int tid = threadIdx.x;
    const int m0 = blockIdx.x * 64, n0 = blockIdx.y * 64;
    const int ty = tid >> 4, tx = tid & 15;
    const int lr = tid >> 2, lc = (tid & 3) << 2;

    float acc[4][4];
#pragma unroll
    for (int i = 0; i < 4; ++i)
#pragma unroll
        for (int j = 0; j < 4; ++j) acc[i][j] = 0.0f;

    for (int k0 = 0; k0 < CC; k0 += 16) {
        float4 av = *reinterpret_cast<const float4*>(&a[(size_t)(m0 + lr) * CC + k0 + lc]);
        float4 wv = *reinterpret_cast<const float4*>(&w[(size_t)(n0 + lr) * CC + k0 + lc]);
        __syncthreads();
        a_lds[lr][lc + 0] = av.x; a_lds[lr][lc + 1] = av.y;
        a_lds[lr][lc + 2] = av.z; a_lds[lr][lc + 3] = av.w;
        b_lds[lr][lc + 0] = wv.x; b_lds[lr][lc + 1] = wv.y;
        b_lds[lr][lc + 2] = wv.z; b_lds[lr][lc + 3] = wv.w;
        __syncthreads();
#pragma unroll
        for (int kk = 0; kk < 16; ++kk) {
            float a0 = a_lds[ty + 0][kk];
            float a1 = a_lds[ty + 16][kk];
            float a2 = a_lds[ty + 32][kk];
            float a3 = a_lds[ty + 48][kk];
            float w0 = b_lds[tx + 0][kk];
            float w1 = b_lds[tx + 16][kk];
            float w2 = b_lds[tx + 32][kk];
            float w3 = b_lds[tx + 48][kk];
            acc[0][0] = fmaf(a0, w0, acc[0][0]); acc[0][1] = fmaf(a0, w1, acc[0][1]);
            acc[0][2] = fmaf(a0, w2, acc[0][2]); acc[0][3] = fmaf(a0, w3, acc[0][3]);
            acc[1][0] = fmaf(a1, w0, acc[1][0]); acc[1][1] = fmaf(a1, w1, acc[1][1]);
            acc[1][2] = fmaf(a1, w2, acc[1][2]); acc[1][3] = fmaf(a1, w3, acc[1][3]);
            acc[2][0] = fmaf(a2, w0, acc[2][0]); acc[2][1] = fmaf(a2, w1, acc[2][1]);
            acc[2][2] = fmaf(a2, w2, acc[2][2]); acc[2][3] = fmaf(a2, w3, acc[2][3]);
            acc[3][0] = fmaf(a3, w0, acc[3][0]); acc[3][1] = fmaf(a3, w1, acc[3][1]);
            acc[3][2] = fmaf(a3, w2, acc[3][2]); acc[3][3] = fmaf(a3, w3, acc[3][3]);
        }
    }

#pragma unroll
    for (int i = 0; i < 4; ++i) {
#pragma unroll
        for (int j = 0; j < 4; ++j) {
            int m = m0 + ty + i * 16;
            int n = n0 + tx + j * 16;
            out[(size_t)m * CC + n] = acc[i][j] + bias[n];
        }
    }
}

extern "C" void kernel_launch(void* const* d_in, const int* in_sizes, int n_in,
                              void* d_out, int out_size, void* d_ws, size_t ws_size,
                              hipStream_t stream) {
    const float* x     = (const float*)d_in[0];
    const float* w_in  = (const float*)d_in[1];
    const float* b_in  = (const float*)d_in[2];
    const float* w_out = (const float*)d_in[3];
    const float* b_out = (const float*)d_in[4];

    float* xout     = (float*)d_out;                        // [B][N][C]
    float* attn_out = (float*)d_out + (size_t)BB * NN * CC; // [B][H][N][N]

    char* ws = (char*)d_ws;
    double* qws  = (double*)ws;                                   // 25,165,824 B
    double* kws  = (double*)(ws + 25165824);                      // 25,165,824 B
    float*  vws  = (float*)(ws + 50331648);                       // 12,582,912 B
    float*  xatt = (float*)(ws + 62914560);                       // 12,582,912 B

    hipLaunchKernelGGL(qk_proj, dim3(64, 24), dim3(256), 0, stream,
                       x, w_in, b_in, qws, kws);
    hipLaunchKernelGGL(v_proj, dim3(64, 12), dim3(256), 0, stream,
                       x, w_in, b_in, vws);
    hipLaunchKernelGGL(scores32, dim3(NN / 64, BB * HH), dim3(256), 0, stream,
                       qws, kws, attn_out);
    hipLaunchKernelGGL(topk_select, dim3(BB * HH * (NN / 4)), dim3(256), 0, stream,
                       qws, kws, vws, attn_out, xatt);
    hipLaunchKernelGGL(out_proj, dim3(64, 12), dim3(256), 0, stream,
                       xatt, w_out, b_out, xout);
}